// Round 2
// baseline (2407.606 us; speedup 1.0000x reference)
//
#include <hip/hip_runtime.h>
#include <hip/hip_bf16.h>
#include <cstdint>
#include <cstddef>

// ---------------- sizes ----------------
#define N1 442368   // 48*96*96 spatial (f1, p1)
#define N2 55296    // 24*48*48 spatial (f2, p2)
#define N3 6912     // 12*24*24 spatial (f3, p3)

#define KCAND 512
#define CAP   4096

// ---------------- helpers ----------------
__device__ __forceinline__ unsigned long long f2key64(double f) {
  unsigned long long b = (unsigned long long)__double_as_longlong(f);
  return (b & 0x8000000000000000ULL) ? ~b : (b | 0x8000000000000000ULL);
}

// ---------------- conv1: 1->16ch, in 96x192x192, out 48x96x96 (fp64 acc) ----------------
__global__ void conv1_k(const float* __restrict__ x, const float* __restrict__ w,
                        const float* __restrict__ b, double* __restrict__ f1) {
  __shared__ float ws[16 * 27];
  for (int i = threadIdx.x; i < 16 * 27; i += blockDim.x) ws[i] = w[i];
  __syncthreads();
  int v = blockIdx.x * blockDim.x + threadIdx.x;
  if (v >= N1) return;
  int z = v / (96 * 96); int r = v % (96 * 96); int y = r / 96; int xo = r % 96;
  double acc[16];
#pragma unroll
  for (int c = 0; c < 16; c++) acc[c] = (double)b[c];
  for (int dz = 0; dz < 3; dz++) {
    int zi = 2 * z + dz; if (zi >= 96) break;
    for (int dy = 0; dy < 3; dy++) {
      int yi = 2 * y + dy; if (yi >= 192) break;
      for (int dx = 0; dx < 3; dx++) {
        int xi = 2 * xo + dx; if (xi >= 192) break;
        double vv = (double)x[(zi * 192 + yi) * 192 + xi];
        int t = (dz * 3 + dy) * 3 + dx;
#pragma unroll
        for (int c = 0; c < 16; c++) acc[c] = fma(vv, (double)ws[c * 27 + t], acc[c]);
      }
    }
  }
#pragma unroll
  for (int c = 0; c < 16; c++) f1[(size_t)c * N1 + v] = fmax(acc[c], 0.0);
}

// ---------------- conv2: 16->32ch, in 48x96x96, out 24x48x48 (fp64) ----------------
__global__ void conv2_k(const double* __restrict__ f1, const float* __restrict__ w,
                        const float* __restrict__ b, double* __restrict__ f2) {
  __shared__ float ws[32 * 16 * 27];
  for (int i = threadIdx.x; i < 32 * 16 * 27; i += blockDim.x) ws[i] = w[i];
  __syncthreads();
  int v = blockIdx.x * blockDim.x + threadIdx.x;
  if (v >= N2) return;
  int z = v / (48 * 48); int r = v % (48 * 48); int y = r / 48; int xo = r % 48;
  double acc[32];
#pragma unroll
  for (int c = 0; c < 32; c++) acc[c] = (double)b[c];
  for (int ci = 0; ci < 16; ci++) {
    const double* fp = f1 + (size_t)ci * N1;
    for (int dz = 0; dz < 3; dz++) {
      int zi = 2 * z + dz; if (zi >= 48) break;
      for (int dy = 0; dy < 3; dy++) {
        int yi = 2 * y + dy; if (yi >= 96) break;
        for (int dx = 0; dx < 3; dx++) {
          int xi = 2 * xo + dx; if (xi >= 96) break;
          double vv = fp[(zi * 96 + yi) * 96 + xi];
          int t = (dz * 3 + dy) * 3 + dx;
#pragma unroll
          for (int c = 0; c < 32; c++) acc[c] = fma(vv, (double)ws[(c * 16 + ci) * 27 + t], acc[c]);
        }
      }
    }
  }
#pragma unroll
  for (int c = 0; c < 32; c++) f2[(size_t)c * N2 + v] = fmax(acc[c], 0.0);
}

// ---------------- conv3: 32->64ch, out 12x24x24; gridDim.y=4 groups of 16 (fp64) ----------------
__global__ void conv3_k(const double* __restrict__ f2, const float* __restrict__ w,
                        const float* __restrict__ b, double* __restrict__ f3) {
  __shared__ float ws[16 * 32 * 27];
  int g = blockIdx.y;
  for (int i = threadIdx.x; i < 16 * 32 * 27; i += blockDim.x) ws[i] = w[g * (16 * 32 * 27) + i];
  __syncthreads();
  int v = blockIdx.x * blockDim.x + threadIdx.x;
  if (v >= N3) return;
  int z = v / (24 * 24); int r = v % (24 * 24); int y = r / 24; int xo = r % 24;
  double acc[16];
#pragma unroll
  for (int c = 0; c < 16; c++) acc[c] = (double)b[g * 16 + c];
  for (int ci = 0; ci < 32; ci++) {
    const double* fp = f2 + (size_t)ci * N2;
    for (int dz = 0; dz < 3; dz++) {
      int zi = 2 * z + dz; if (zi >= 24) break;
      for (int dy = 0; dy < 3; dy++) {
        int yi = 2 * y + dy; if (yi >= 48) break;
        for (int dx = 0; dx < 3; dx++) {
          int xi = 2 * xo + dx; if (xi >= 48) break;
          double vv = fp[(zi * 48 + yi) * 48 + xi];
          int t = (dz * 3 + dy) * 3 + dx;
#pragma unroll
          for (int c = 0; c < 16; c++) acc[c] = fma(vv, (double)ws[(c * 32 + ci) * 27 + t], acc[c]);
        }
      }
    }
  }
#pragma unroll
  for (int c = 0; c < 16; c++) f3[(size_t)(g * 16 + c) * N3 + v] = fmax(acc[c], 0.0);
}

// ---------------- p3 = l3(f3); score3 (fp64; also fp32 copy for cubes) ----------------
__global__ void p3_k(const double* __restrict__ f3, const float* __restrict__ w,
                     const float* __restrict__ b, double* __restrict__ p3d,
                     float* __restrict__ p3f, double* __restrict__ s3) {
  __shared__ float ws[32 * 64];
  for (int i = threadIdx.x; i < 32 * 64; i += blockDim.x) ws[i] = w[i];
  __syncthreads();
  int v = blockIdx.x * blockDim.x + threadIdx.x;
  if (v >= N3) return;
  double acc[32];
#pragma unroll
  for (int c = 0; c < 32; c++) acc[c] = (double)b[c];
  for (int ci = 0; ci < 64; ci++) {
    double vv = f3[(size_t)ci * N3 + v];
#pragma unroll
    for (int c = 0; c < 32; c++) acc[c] = fma(vv, (double)ws[c * 64 + ci], acc[c]);
  }
  double m = -1e300;
#pragma unroll
  for (int c = 0; c < 32; c++) {
    p3d[(size_t)c * N3 + v] = acc[c];
    p3f[(size_t)c * N3 + v] = (float)acc[c];
    m = fmax(m, acc[c]);
  }
  s3[v] = m;
}

// ---------------- p2 = l2(f2) + up2(p3); score2 ----------------
__global__ void p2_k(const double* __restrict__ f2, const float* __restrict__ w,
                     const float* __restrict__ b, const double* __restrict__ p3d,
                     double* __restrict__ p2d, float* __restrict__ p2f, double* __restrict__ s2) {
  __shared__ float ws[32 * 32];
  for (int i = threadIdx.x; i < 32 * 32; i += blockDim.x) ws[i] = w[i];
  __syncthreads();
  int v = blockIdx.x * blockDim.x + threadIdx.x;
  if (v >= N2) return;
  int z = v / (48 * 48); int r = v % (48 * 48); int y = r / 48; int xo = r % 48;
  int up = ((z >> 1) * 24 + (y >> 1)) * 24 + (xo >> 1);
  double acc[32];
#pragma unroll
  for (int c = 0; c < 32; c++) acc[c] = (double)b[c];
  for (int ci = 0; ci < 32; ci++) {
    double vv = f2[(size_t)ci * N2 + v];
#pragma unroll
    for (int c = 0; c < 32; c++) acc[c] = fma(vv, (double)ws[c * 32 + ci], acc[c]);
  }
  double m = -1e300;
#pragma unroll
  for (int c = 0; c < 32; c++) {
    double o = acc[c] + p3d[(size_t)c * N3 + up];
    p2d[(size_t)c * N2 + v] = o;
    p2f[(size_t)c * N2 + v] = (float)o;
    m = fmax(m, o);
  }
  s2[v] = m;
}

// ---------------- p1 = l1(f1) + up2(p2); score1 (fp32 p1 only + fp64 score) ----------------
__global__ void p1_k(const double* __restrict__ f1, const float* __restrict__ w,
                     const float* __restrict__ b, const double* __restrict__ p2d,
                     float* __restrict__ p1f, double* __restrict__ s1) {
  __shared__ float ws[32 * 16];
  for (int i = threadIdx.x; i < 32 * 16; i += blockDim.x) ws[i] = w[i];
  __syncthreads();
  int v = blockIdx.x * blockDim.x + threadIdx.x;
  if (v >= N1) return;
  int z = v / (96 * 96); int r = v % (96 * 96); int y = r / 96; int xo = r % 96;
  int up = ((z >> 1) * 48 + (y >> 1)) * 48 + (xo >> 1);
  double acc[32];
#pragma unroll
  for (int c = 0; c < 32; c++) acc[c] = (double)b[c];
  for (int ci = 0; ci < 16; ci++) {
    double vv = f1[(size_t)ci * N1 + v];
#pragma unroll
    for (int c = 0; c < 32; c++) acc[c] = fma(vv, (double)ws[c * 16 + ci], acc[c]);
  }
  double m = -1e300;
#pragma unroll
  for (int c = 0; c < 32; c++) {
    double o = acc[c] + p2d[(size_t)c * N2 + up];
    p1f[(size_t)c * N1 + v] = (float)o;
    m = fmax(m, o);
  }
  s1[v] = m;
}

// ---------------- top-k selection pipeline (fp64 keys) ----------------
__global__ void hist_k(const double* __restrict__ s, int n, unsigned* __restrict__ hist) {
  int i = blockIdx.x * blockDim.x + threadIdx.x;
  if (i < n) atomicAdd(&hist[(unsigned)(f2key64(s[i]) >> 48)], 1u);
}

__global__ void findbin_k(const unsigned* __restrict__ hist, unsigned* __restrict__ Bbin) {
  __shared__ unsigned sums[1024];
  __shared__ unsigned suffix[1024];
  int t = threadIdx.x;
  unsigned s = 0;
  for (int b = 0; b < 64; b++) s += hist[t * 64 + b];
  sums[t] = s;
  __syncthreads();
  if (t == 0) {
    unsigned run = 0;
    for (int i = 1023; i >= 0; i--) { suffix[i] = run; run += sums[i]; }
  }
  __syncthreads();
  unsigned above = suffix[t];
  if (above < (unsigned)KCAND && above + sums[t] >= (unsigned)KCAND) {
    unsigned run = above; int B = t * 64;
    for (int b = t * 64 + 63; b >= t * 64; b--) {
      run += hist[b];
      if (run >= (unsigned)KCAND) { B = b; break; }
    }
    *Bbin = (unsigned)B;
  }
}

__global__ void compact_k(const double* __restrict__ s, int n, const unsigned* __restrict__ Bbin,
                          unsigned long long* __restrict__ ck, unsigned* __restrict__ cidx,
                          unsigned* __restrict__ cnt) {
  int i = blockIdx.x * blockDim.x + threadIdx.x;
  if (i >= n) return;
  unsigned long long key = f2key64(s[i]);
  if ((unsigned)(key >> 48) >= *Bbin) {
    unsigned pos = atomicAdd(cnt, 1u);
    if (pos < (unsigned)CAP) { ck[pos] = key; cidx[pos] = (unsigned)i; }
  }
}

// one-block bitonic sort: (score desc, idx asc); emits top-512 (idx, valid)
__global__ void sort_k(const unsigned long long* __restrict__ ck, const unsigned* __restrict__ cidx,
                       const unsigned* __restrict__ cnt, uint2* __restrict__ topk) {
  __shared__ unsigned long long k_[CAP];
  __shared__ unsigned x_[CAP];
  int t = threadIdx.x;
  unsigned m = *cnt; if (m > (unsigned)CAP) m = CAP;
  int sz = 512; while (sz < (int)m) sz <<= 1;   // m >= 512 guaranteed
  for (int i = t; i < sz; i += 1024) {
    if (i < (int)m) { k_[i] = ck[i]; x_[i] = cidx[i]; }
    else            { k_[i] = 0ULL;  x_[i] = 0xFFFFFFFFu; }
  }
  __syncthreads();
  for (int kk = 2; kk <= sz; kk <<= 1) {
    for (int j = kk >> 1; j > 0; j >>= 1) {
      for (int i = t; i < sz; i += 1024) {
        int l = i ^ j;
        if (l > i) {
          unsigned long long ka = k_[i], kb = k_[l];
          unsigned ia = x_[i], ib = x_[l];
          bool b_first = (kb > ka) || (kb == ka && ib < ia);  // b ranks before a?
          bool up = (i & kk) == 0;                            // descending region
          if (up == b_first) { k_[i] = kb; x_[i] = ib; k_[l] = ka; x_[l] = ia; }
        }
      }
      __syncthreads();
    }
  }
  if (t < KCAND) {
    unsigned long long key = k_[t];
    unsigned long long bb = (key >> 63) ? (key & 0x7FFFFFFFFFFFFFFFULL) : ~key;
    double sc = __longlong_as_double((long long)bb);
    topk[t] = make_uint2(x_[t], sc > 0.5 ? 1u : 0u);
  }
}

// ---------------- per-candidate cube stats + MLP (fp64 math, fp32 data) ----------------
__global__ __launch_bounds__(64) void mlp_k(const uint2* __restrict__ topk,
                                            const float* __restrict__ p, int D, int H, int W,
                                            const float* __restrict__ w1, const float* __restrict__ b1,
                                            const float* __restrict__ w2, const float* __restrict__ b2,
                                            float* __restrict__ out, int rowbase) {
  __shared__ double lhi[64];
  int s = blockIdx.x;
  uint2 e = topk[s];
  unsigned idx = e.x;
  double valid = e.y ? 1.0 : 0.0;
  int HW = H * W;
  int z = (int)(idx / (unsigned)HW);
  int r = (int)(idx % (unsigned)HW);
  int y = r / W; int x = r % W;
  int zs = min(max(z - 2, 0), D - 4);
  int ys = min(max(y - 2, 0), H - 4);
  int xs = min(max(x - 2, 0), W - 4);
  int t = threadIdx.x;
  int c = t & 31, h = t >> 5;
  const float* pc = p + (size_t)c * D * HW;
  double sum = 0.0, ss = 0.0;
  for (int i = 0; i < 32; i++) {
    int vv = h * 32 + i;
    int dz = vv >> 4, dy = (vv >> 2) & 3, dx = vv & 3;
    double val = (double)pc[(zs + dz) * HW + (ys + dy) * W + (xs + dx)];
    sum += val; ss = fma(val, val, ss);
  }
  sum += __shfl_xor(sum, 32);
  ss  += __shfl_xor(ss, 32);
  if (h == 0) {
    double mean = sum * (1.0 / 64.0);
    double var = ss * (1.0 / 64.0) - mean * mean;
    lhi[c] = mean;
    lhi[32 + c] = sqrt(var + 1e-6);
  }
  __syncthreads();
  double h0 = (double)b1[t], h1 = (double)b1[t + 64];
  for (int i = 0; i < 64; i++) {
    double li = lhi[i];
    h0 = fma(li, (double)w1[i * 128 + t], h0);
    h1 = fma(li, (double)w1[i * 128 + t + 64], h1);
  }
  h0 = fmax(h0, 0.0); h1 = fmax(h1, 0.0);
  double o0 = h0 * (double)w2[t * 2 + 0] + h1 * (double)w2[(t + 64) * 2 + 0];
  double o1 = h0 * (double)w2[t * 2 + 1] + h1 * (double)w2[(t + 64) * 2 + 1];
  for (int o = 1; o < 64; o <<= 1) { o0 += __shfl_xor(o0, o); o1 += __shfl_xor(o1, o); }
  if (t == 0) {
    out[(size_t)(rowbase + s) * 2 + 0] = (float)((o0 + (double)b2[0]) * valid);
    out[(size_t)(rowbase + s) * 2 + 1] = (float)((o1 + (double)b2[1]) * valid);
  }
}

// ---------------- launch ----------------
extern "C" void kernel_launch(void* const* d_in, const int* in_sizes, int n_in,
                              void* d_out, int out_size, void* d_ws, size_t ws_size,
                              hipStream_t stream) {
  const float* x   = (const float*)d_in[0];
  const float* c1w = (const float*)d_in[1];  const float* c1b = (const float*)d_in[2];
  const float* c2w = (const float*)d_in[3];  const float* c2b = (const float*)d_in[4];
  const float* c3w = (const float*)d_in[5];  const float* c3b = (const float*)d_in[6];
  const float* l1w = (const float*)d_in[7];  const float* l1b = (const float*)d_in[8];
  const float* l2w = (const float*)d_in[9];  const float* l2b = (const float*)d_in[10];
  const float* l3w = (const float*)d_in[11]; const float* l3b = (const float*)d_in[12];
  const float* w1  = (const float*)d_in[13]; const float* b1  = (const float*)d_in[14];
  const float* w2  = (const float*)d_in[15]; const float* b2  = (const float*)d_in[16];
  float* out = (float*)d_out;

  char* ws = (char*)d_ws;
  size_t off = 0;
  auto take = [&](size_t bytes) { size_t o = off; off = (off + bytes + 255) & ~(size_t)255; return o; };
  double* f1d = (double*)(ws + take((size_t)16 * N1 * 8));
  double* f2d = (double*)(ws + take((size_t)32 * N2 * 8));
  double* f3d = (double*)(ws + take((size_t)64 * N3 * 8));
  float*  p1f = (float*) (ws + take((size_t)32 * N1 * 4));
  double* p2d = (double*)(ws + take((size_t)32 * N2 * 8));
  float*  p2f = (float*) (ws + take((size_t)32 * N2 * 4));
  double* p3d = (double*)(ws + take((size_t)32 * N3 * 8));
  float*  p3f = (float*) (ws + take((size_t)32 * N3 * 4));
  double* s1 = (double*)(ws + take((size_t)N1 * 8));
  double* s2 = (double*)(ws + take((size_t)N2 * 8));
  double* s3 = (double*)(ws + take((size_t)N3 * 8));
  size_t histOff = take(3 * 65536 * 4 + 3 * 4 + 3 * 4);
  unsigned* hist = (unsigned*)(ws + histOff);
  unsigned* cnt  = hist + 3 * 65536;
  unsigned* Bbin = cnt + 3;
  unsigned long long* candKey = (unsigned long long*)(ws + take((size_t)3 * CAP * 8));
  unsigned* candIdx = (unsigned*)(ws + take((size_t)3 * CAP * 4));
  uint2* topk = (uint2*)(ws + take((size_t)3 * KCAND * 8));

  // zero hist + counters (Bbin written unconditionally by findbin)
  hipMemsetAsync(ws + histOff, 0, 3 * 65536 * 4 + 3 * 4, stream);

  // encoder (fp64)
  conv1_k<<<N1 / 256, 256, 0, stream>>>(x, c1w, c1b, f1d);
  conv2_k<<<N2 / 256, 256, 0, stream>>>(f1d, c2w, c2b, f2d);
  conv3_k<<<dim3(N3 / 256, 4), 256, 0, stream>>>(f2d, c3w, c3b, f3d);
  // FPN top-down (fp64 + fp32 copies)
  p3_k<<<N3 / 256, 256, 0, stream>>>(f3d, l3w, l3b, p3d, p3f, s3);
  p2_k<<<N2 / 256, 256, 0, stream>>>(f2d, l2w, l2b, p3d, p2d, p2f, s2);
  p1_k<<<N1 / 256, 256, 0, stream>>>(f1d, l1w, l1b, p2d, p1f, s1);

  struct Lvl { const float* p; const double* s; int n, D, H, W, rowbase; };
  Lvl lv[3] = {
    { p1f, s1, N1, 48, 96, 96, 0 },
    { p2f, s2, N2, 24, 48, 48, KCAND },
    { p3f, s3, N3, 12, 24, 24, 2 * KCAND },
  };
  for (int L = 0; L < 3; L++) {
    unsigned* h = hist + L * 65536;
    unsigned* c = cnt + L;
    unsigned* B = Bbin + L;
    unsigned long long* ckL = candKey + (size_t)L * CAP;
    unsigned* ciL = candIdx + (size_t)L * CAP;
    uint2* tkL = topk + (size_t)L * KCAND;
    hist_k<<<lv[L].n / 256, 256, 0, stream>>>(lv[L].s, lv[L].n, h);
    findbin_k<<<1, 1024, 0, stream>>>(h, B);
    compact_k<<<lv[L].n / 256, 256, 0, stream>>>(lv[L].s, lv[L].n, B, ckL, ciL, c);
    sort_k<<<1, 1024, 0, stream>>>(ckL, ciL, c, tkL);
    mlp_k<<<KCAND, 64, 0, stream>>>(tkL, lv[L].p, lv[L].D, lv[L].H, lv[L].W,
                                    w1, b1, w2, b2, out, lv[L].rowbase);
  }
}

// Round 3
// 955.613 us; speedup vs baseline: 2.5194x; 2.5194x over previous
//
#include <hip/hip_runtime.h>
#include <hip/hip_bf16.h>
#include <cstdint>
#include <cstddef>

// ---------------- sizes ----------------
#define N1 442368   // 48*96*96 spatial (f1, p1)
#define N2 55296    // 24*48*48 spatial (f2, p2)
#define N3 6912     // 12*24*24 spatial (f3, p3)

#define KCAND 512
#define CAP   4096

// ---------------- helpers ----------------
__device__ __forceinline__ unsigned long long f2key64(double f) {
  unsigned long long b = (unsigned long long)__double_as_longlong(f);
  return (b & 0x8000000000000000ULL) ? ~b : (b | 0x8000000000000000ULL);
}
__device__ __forceinline__ unsigned f2key32(float f) {
  unsigned b = __float_as_uint(f);
  return (b & 0x80000000u) ? ~b : (b | 0x80000000u);
}

// ---------------- conv1: 1->16ch, in 96x192x192, out 48x96x96 (fp64 acc) ----------------
__global__ void conv1_k(const float* __restrict__ x, const float* __restrict__ w,
                        const float* __restrict__ b, double* __restrict__ f1) {
  __shared__ float ws[16 * 27];
  for (int i = threadIdx.x; i < 16 * 27; i += blockDim.x) ws[i] = w[i];
  __syncthreads();
  int v = blockIdx.x * blockDim.x + threadIdx.x;
  if (v >= N1) return;
  int z = v / (96 * 96); int r = v % (96 * 96); int y = r / 96; int xo = r % 96;
  double acc[16];
#pragma unroll
  for (int c = 0; c < 16; c++) acc[c] = (double)b[c];
  for (int dz = 0; dz < 3; dz++) {
    int zi = 2 * z + dz; if (zi >= 96) break;
    for (int dy = 0; dy < 3; dy++) {
      int yi = 2 * y + dy; if (yi >= 192) break;
      for (int dx = 0; dx < 3; dx++) {
        int xi = 2 * xo + dx; if (xi >= 192) break;
        double vv = (double)x[(zi * 192 + yi) * 192 + xi];
        int t = (dz * 3 + dy) * 3 + dx;
#pragma unroll
        for (int c = 0; c < 16; c++) acc[c] = fma(vv, (double)ws[c * 27 + t], acc[c]);
      }
    }
  }
#pragma unroll
  for (int c = 0; c < 16; c++) f1[(size_t)c * N1 + v] = fmax(acc[c], 0.0);
}

// ---------------- conv2: 16->32ch, in 48x96x96, out 24x48x48 (fp64) ----------------
__global__ void conv2_k(const double* __restrict__ f1, const float* __restrict__ w,
                        const float* __restrict__ b, double* __restrict__ f2) {
  __shared__ float ws[32 * 16 * 27];
  for (int i = threadIdx.x; i < 32 * 16 * 27; i += blockDim.x) ws[i] = w[i];
  __syncthreads();
  int v = blockIdx.x * blockDim.x + threadIdx.x;
  if (v >= N2) return;
  int z = v / (48 * 48); int r = v % (48 * 48); int y = r / 48; int xo = r % 48;
  double acc[32];
#pragma unroll
  for (int c = 0; c < 32; c++) acc[c] = (double)b[c];
  for (int ci = 0; ci < 16; ci++) {
    const double* fp = f1 + (size_t)ci * N1;
    for (int dz = 0; dz < 3; dz++) {
      int zi = 2 * z + dz; if (zi >= 48) break;
      for (int dy = 0; dy < 3; dy++) {
        int yi = 2 * y + dy; if (yi >= 96) break;
        for (int dx = 0; dx < 3; dx++) {
          int xi = 2 * xo + dx; if (xi >= 96) break;
          double vv = fp[(zi * 96 + yi) * 96 + xi];
          int t = (dz * 3 + dy) * 3 + dx;
#pragma unroll
          for (int c = 0; c < 32; c++) acc[c] = fma(vv, (double)ws[(c * 16 + ci) * 27 + t], acc[c]);
        }
      }
    }
  }
#pragma unroll
  for (int c = 0; c < 32; c++) f2[(size_t)c * N2 + v] = fmax(acc[c], 0.0);
}

// ---------------- conv3: 32->64ch, out 12x24x24; gridDim.y=4 groups of 16 (fp64) ----------------
__global__ void conv3_k(const double* __restrict__ f2, const float* __restrict__ w,
                        const float* __restrict__ b, double* __restrict__ f3) {
  __shared__ float ws[16 * 32 * 27];
  int g = blockIdx.y;
  for (int i = threadIdx.x; i < 16 * 32 * 27; i += blockDim.x) ws[i] = w[g * (16 * 32 * 27) + i];
  __syncthreads();
  int v = blockIdx.x * blockDim.x + threadIdx.x;
  if (v >= N3) return;
  int z = v / (24 * 24); int r = v % (24 * 24); int y = r / 24; int xo = r % 24;
  double acc[16];
#pragma unroll
  for (int c = 0; c < 16; c++) acc[c] = (double)b[g * 16 + c];
  for (int ci = 0; ci < 32; ci++) {
    const double* fp = f2 + (size_t)ci * N2;
    for (int dz = 0; dz < 3; dz++) {
      int zi = 2 * z + dz; if (zi >= 24) break;
      for (int dy = 0; dy < 3; dy++) {
        int yi = 2 * y + dy; if (yi >= 48) break;
        for (int dx = 0; dx < 3; dx++) {
          int xi = 2 * xo + dx; if (xi >= 48) break;
          double vv = fp[(zi * 48 + yi) * 48 + xi];
          int t = (dz * 3 + dy) * 3 + dx;
#pragma unroll
          for (int c = 0; c < 16; c++) acc[c] = fma(vv, (double)ws[(c * 32 + ci) * 27 + t], acc[c]);
        }
      }
    }
  }
#pragma unroll
  for (int c = 0; c < 16; c++) f3[(size_t)(g * 16 + c) * N3 + v] = fmax(acc[c], 0.0);
}

// ---------------- p3 = l3(f3); score3 (fp64; also fp32 copy for cubes) ----------------
__global__ void p3_k(const double* __restrict__ f3, const float* __restrict__ w,
                     const float* __restrict__ b, double* __restrict__ p3d,
                     float* __restrict__ p3f, double* __restrict__ s3) {
  __shared__ float ws[32 * 64];
  for (int i = threadIdx.x; i < 32 * 64; i += blockDim.x) ws[i] = w[i];
  __syncthreads();
  int v = blockIdx.x * blockDim.x + threadIdx.x;
  if (v >= N3) return;
  double acc[32];
#pragma unroll
  for (int c = 0; c < 32; c++) acc[c] = (double)b[c];
  for (int ci = 0; ci < 64; ci++) {
    double vv = f3[(size_t)ci * N3 + v];
#pragma unroll
    for (int c = 0; c < 32; c++) acc[c] = fma(vv, (double)ws[c * 64 + ci], acc[c]);
  }
  double m = -1e300;
#pragma unroll
  for (int c = 0; c < 32; c++) {
    p3d[(size_t)c * N3 + v] = acc[c];
    p3f[(size_t)c * N3 + v] = (float)acc[c];
    m = fmax(m, acc[c]);
  }
  s3[v] = m;
}

// ---------------- p2 = l2(f2) + up2(p3); score2 ----------------
__global__ void p2_k(const double* __restrict__ f2, const float* __restrict__ w,
                     const float* __restrict__ b, const double* __restrict__ p3d,
                     double* __restrict__ p2d, float* __restrict__ p2f, double* __restrict__ s2) {
  __shared__ float ws[32 * 32];
  for (int i = threadIdx.x; i < 32 * 32; i += blockDim.x) ws[i] = w[i];
  __syncthreads();
  int v = blockIdx.x * blockDim.x + threadIdx.x;
  if (v >= N2) return;
  int z = v / (48 * 48); int r = v % (48 * 48); int y = r / 48; int xo = r % 48;
  int up = ((z >> 1) * 24 + (y >> 1)) * 24 + (xo >> 1);
  double acc[32];
#pragma unroll
  for (int c = 0; c < 32; c++) acc[c] = (double)b[c];
  for (int ci = 0; ci < 32; ci++) {
    double vv = f2[(size_t)ci * N2 + v];
#pragma unroll
    for (int c = 0; c < 32; c++) acc[c] = fma(vv, (double)ws[c * 32 + ci], acc[c]);
  }
  double m = -1e300;
#pragma unroll
  for (int c = 0; c < 32; c++) {
    double o = acc[c] + p3d[(size_t)c * N3 + up];
    p2d[(size_t)c * N2 + v] = o;
    p2f[(size_t)c * N2 + v] = (float)o;
    m = fmax(m, o);
  }
  s2[v] = m;
}

// ---------------- p1 = l1(f1) + up2(p2); score1 (fp32 p1 only + fp64 score) ----------------
__global__ void p1_k(const double* __restrict__ f1, const float* __restrict__ w,
                     const float* __restrict__ b, const double* __restrict__ p2d,
                     float* __restrict__ p1f, double* __restrict__ s1) {
  __shared__ float ws[32 * 16];
  for (int i = threadIdx.x; i < 32 * 16; i += blockDim.x) ws[i] = w[i];
  __syncthreads();
  int v = blockIdx.x * blockDim.x + threadIdx.x;
  if (v >= N1) return;
  int z = v / (96 * 96); int r = v % (96 * 96); int y = r / 96; int xo = r % 96;
  int up = ((z >> 1) * 48 + (y >> 1)) * 48 + (xo >> 1);
  double acc[32];
#pragma unroll
  for (int c = 0; c < 32; c++) acc[c] = (double)b[c];
  for (int ci = 0; ci < 16; ci++) {
    double vv = f1[(size_t)ci * N1 + v];
#pragma unroll
    for (int c = 0; c < 32; c++) acc[c] = fma(vv, (double)ws[c * 16 + ci], acc[c]);
  }
  double m = -1e300;
#pragma unroll
  for (int c = 0; c < 32; c++) {
    double o = acc[c] + p2d[(size_t)c * N2 + up];
    p1f[(size_t)c * N1 + v] = (float)o;
    m = fmax(m, o);
  }
  s1[v] = m;
}

// ---------------- selection: two-pass 256-bin radix over fp32 key, batched over levels ----------------
// (float)(double) is monotone, so fp32-key binning selects a superset of the fp64 top-512.
// meta[L*4+0]=b1, +1=countAbove, +2=T (16-bit fp32-key threshold << 16)

__global__ void hist1_k(const double* __restrict__ s1, const double* __restrict__ s2,
                        const double* __restrict__ s3, unsigned* __restrict__ hist) {
  int L = blockIdx.y;
  const double* s = L == 0 ? s1 : (L == 1 ? s2 : s3);
  int n = L == 0 ? N1 : (L == 1 ? N2 : N3);
  unsigned* hg = hist + L * 256;
  __shared__ unsigned h[256];
  h[threadIdx.x] = 0;
  __syncthreads();
  for (int i = blockIdx.x * 256 + threadIdx.x; i < n; i += gridDim.x * 256)
    atomicAdd(&h[f2key32((float)s[i]) >> 24], 1u);
  __syncthreads();
  unsigned v = h[threadIdx.x];
  if (v) atomicAdd(&hg[threadIdx.x], v);
}

__global__ void pick1_k(const unsigned* __restrict__ hist, unsigned* __restrict__ meta) {
  int L = threadIdx.x;
  if (L >= 3) return;
  const unsigned* hg = hist + L * 256;
  unsigned run = 0; int b = 0;
  for (int i = 255; i >= 0; i--) {
    unsigned c = hg[i];
    if (run + c >= (unsigned)KCAND) { b = i; break; }
    run += c;
  }
  meta[L * 4 + 0] = (unsigned)b;
  meta[L * 4 + 1] = run;
}

__global__ void hist2_k(const double* __restrict__ s1, const double* __restrict__ s2,
                        const double* __restrict__ s3, const unsigned* __restrict__ meta,
                        unsigned* __restrict__ hist2) {
  int L = blockIdx.y;
  const double* s = L == 0 ? s1 : (L == 1 ? s2 : s3);
  int n = L == 0 ? N1 : (L == 1 ? N2 : N3);
  unsigned b1 = meta[L * 4 + 0];
  unsigned* hg = hist2 + L * 256;
  __shared__ unsigned h[256];
  h[threadIdx.x] = 0;
  __syncthreads();
  for (int i = blockIdx.x * 256 + threadIdx.x; i < n; i += gridDim.x * 256) {
    unsigned k = f2key32((float)s[i]);
    if ((k >> 24) == b1) atomicAdd(&h[(k >> 16) & 255u], 1u);
  }
  __syncthreads();
  unsigned v = h[threadIdx.x];
  if (v) atomicAdd(&hg[threadIdx.x], v);
}

__global__ void pick2_k(const unsigned* __restrict__ hist2, unsigned* __restrict__ meta) {
  int L = threadIdx.x;
  if (L >= 3) return;
  const unsigned* hg = hist2 + L * 256;
  unsigned b1 = meta[L * 4 + 0];
  unsigned run = meta[L * 4 + 1];
  unsigned b2 = 0;
  for (int i = 255; i >= 0; i--) {
    run += hg[i];
    if (run >= (unsigned)KCAND) { b2 = (unsigned)i; break; }
  }
  meta[L * 4 + 2] = (b1 << 24) | (b2 << 16);
}

__global__ void compact_k(const double* __restrict__ s1, const double* __restrict__ s2,
                          const double* __restrict__ s3, const unsigned* __restrict__ meta,
                          unsigned long long* __restrict__ ck, unsigned* __restrict__ cidx,
                          unsigned* __restrict__ cnt) {
  int L = blockIdx.y;
  const double* s = L == 0 ? s1 : (L == 1 ? s2 : s3);
  int n = L == 0 ? N1 : (L == 1 ? N2 : N3);
  unsigned T = meta[L * 4 + 2];
  for (int i = blockIdx.x * 256 + threadIdx.x; i < n; i += gridDim.x * 256) {
    double v = s[i];
    if (f2key32((float)v) >= T) {
      unsigned pos = atomicAdd(&cnt[L], 1u);
      if (pos < (unsigned)CAP) {
        ck[(size_t)L * CAP + pos] = f2key64(v);
        cidx[(size_t)L * CAP + pos] = (unsigned)i;
      }
    }
  }
}

// one-block-per-level bitonic sort: (fp64 score desc, idx asc); emits top-512 (idx, valid)
__global__ void sort_k(const unsigned long long* __restrict__ ckA, const unsigned* __restrict__ cidxA,
                       const unsigned* __restrict__ cnt, uint2* __restrict__ topkA) {
  __shared__ unsigned long long k_[CAP];
  __shared__ unsigned x_[CAP];
  int L = blockIdx.x;
  const unsigned long long* ck = ckA + (size_t)L * CAP;
  const unsigned* cidx = cidxA + (size_t)L * CAP;
  uint2* topk = topkA + (size_t)L * KCAND;
  int t = threadIdx.x;
  unsigned m = cnt[L]; if (m > (unsigned)CAP) m = CAP;
  int sz = 512; while (sz < (int)m) sz <<= 1;   // m >= 512 guaranteed
  for (int i = t; i < sz; i += 1024) {
    if (i < (int)m) { k_[i] = ck[i]; x_[i] = cidx[i]; }
    else            { k_[i] = 0ULL;  x_[i] = 0xFFFFFFFFu; }
  }
  __syncthreads();
  for (int kk = 2; kk <= sz; kk <<= 1) {
    for (int j = kk >> 1; j > 0; j >>= 1) {
      for (int i = t; i < sz; i += 1024) {
        int l = i ^ j;
        if (l > i) {
          unsigned long long ka = k_[i], kb = k_[l];
          unsigned ia = x_[i], ib = x_[l];
          bool b_first = (kb > ka) || (kb == ka && ib < ia);  // b ranks before a?
          bool up = (i & kk) == 0;                            // descending region
          if (up == b_first) { k_[i] = kb; x_[i] = ib; k_[l] = ka; x_[l] = ia; }
        }
      }
      __syncthreads();
    }
  }
  if (t < KCAND) {
    unsigned long long key = k_[t];
    unsigned long long bb = (key >> 63) ? (key & 0x7FFFFFFFFFFFFFFFULL) : ~key;
    double sc = __longlong_as_double((long long)bb);
    topk[t] = make_uint2(x_[t], sc > 0.5 ? 1u : 0u);
  }
}

// ---------------- per-candidate cube stats + MLP (fp64 math, fp32 data); batched levels ----------------
__global__ __launch_bounds__(64) void mlp_k(const uint2* __restrict__ topkA,
                                            const float* __restrict__ pa, const float* __restrict__ pb,
                                            const float* __restrict__ pc_,
                                            const float* __restrict__ w1, const float* __restrict__ b1,
                                            const float* __restrict__ w2, const float* __restrict__ b2,
                                            float* __restrict__ out) {
  __shared__ double lhi[64];
  int L = blockIdx.y;
  int s = blockIdx.x;
  const float* p = L == 0 ? pa : (L == 1 ? pb : pc_);
  int D = 48 >> L, H = 96 >> L, W = 96 >> L;
  uint2 e = topkA[(size_t)L * KCAND + s];
  unsigned idx = e.x;
  double valid = e.y ? 1.0 : 0.0;
  int HW = H * W;
  int z = (int)(idx / (unsigned)HW);
  int r = (int)(idx % (unsigned)HW);
  int y = r / W; int x = r % W;
  int zs = min(max(z - 2, 0), D - 4);
  int ys = min(max(y - 2, 0), H - 4);
  int xs = min(max(x - 2, 0), W - 4);
  int t = threadIdx.x;
  int c = t & 31, h = t >> 5;
  const float* pc = p + (size_t)c * D * HW;
  double sum = 0.0, ss = 0.0;
  for (int i = 0; i < 32; i++) {
    int vv = h * 32 + i;
    int dz = vv >> 4, dy = (vv >> 2) & 3, dx = vv & 3;
    double val = (double)pc[(zs + dz) * HW + (ys + dy) * W + (xs + dx)];
    sum += val; ss = fma(val, val, ss);
  }
  sum += __shfl_xor(sum, 32);
  ss  += __shfl_xor(ss, 32);
  if (h == 0) {
    double mean = sum * (1.0 / 64.0);
    double var = ss * (1.0 / 64.0) - mean * mean;
    lhi[c] = mean;
    lhi[32 + c] = sqrt(var + 1e-6);
  }
  __syncthreads();
  double h0 = (double)b1[t], h1 = (double)b1[t + 64];
  for (int i = 0; i < 64; i++) {
    double li = lhi[i];
    h0 = fma(li, (double)w1[i * 128 + t], h0);
    h1 = fma(li, (double)w1[i * 128 + t + 64], h1);
  }
  h0 = fmax(h0, 0.0); h1 = fmax(h1, 0.0);
  double o0 = h0 * (double)w2[t * 2 + 0] + h1 * (double)w2[(t + 64) * 2 + 0];
  double o1 = h0 * (double)w2[t * 2 + 1] + h1 * (double)w2[(t + 64) * 2 + 1];
  for (int o = 1; o < 64; o <<= 1) { o0 += __shfl_xor(o0, o); o1 += __shfl_xor(o1, o); }
  if (t == 0) {
    out[((size_t)L * KCAND + s) * 2 + 0] = (float)((o0 + (double)b2[0]) * valid);
    out[((size_t)L * KCAND + s) * 2 + 1] = (float)((o1 + (double)b2[1]) * valid);
  }
}

// ---------------- launch ----------------
extern "C" void kernel_launch(void* const* d_in, const int* in_sizes, int n_in,
                              void* d_out, int out_size, void* d_ws, size_t ws_size,
                              hipStream_t stream) {
  const float* x   = (const float*)d_in[0];
  const float* c1w = (const float*)d_in[1];  const float* c1b = (const float*)d_in[2];
  const float* c2w = (const float*)d_in[3];  const float* c2b = (const float*)d_in[4];
  const float* c3w = (const float*)d_in[5];  const float* c3b = (const float*)d_in[6];
  const float* l1w = (const float*)d_in[7];  const float* l1b = (const float*)d_in[8];
  const float* l2w = (const float*)d_in[9];  const float* l2b = (const float*)d_in[10];
  const float* l3w = (const float*)d_in[11]; const float* l3b = (const float*)d_in[12];
  const float* w1  = (const float*)d_in[13]; const float* b1  = (const float*)d_in[14];
  const float* w2  = (const float*)d_in[15]; const float* b2  = (const float*)d_in[16];
  float* out = (float*)d_out;

  char* ws = (char*)d_ws;
  size_t off = 0;
  auto take = [&](size_t bytes) { size_t o = off; off = (off + bytes + 255) & ~(size_t)255; return o; };
  double* f1d = (double*)(ws + take((size_t)16 * N1 * 8));
  double* f2d = (double*)(ws + take((size_t)32 * N2 * 8));
  double* f3d = (double*)(ws + take((size_t)64 * N3 * 8));
  float*  p1f = (float*) (ws + take((size_t)32 * N1 * 4));
  double* p2d = (double*)(ws + take((size_t)32 * N2 * 8));
  float*  p2f = (float*) (ws + take((size_t)32 * N2 * 4));
  double* p3d = (double*)(ws + take((size_t)32 * N3 * 8));
  float*  p3f = (float*) (ws + take((size_t)32 * N3 * 4));
  double* s1 = (double*)(ws + take((size_t)N1 * 8));
  double* s2 = (double*)(ws + take((size_t)N2 * 8));
  double* s3 = (double*)(ws + take((size_t)N3 * 8));
  // selection scratch: hist1[3*256] hist2[3*256] cnt[3] (zeroed) + meta[12] (always written)
  size_t zOff = take((3 * 256 + 3 * 256 + 3) * 4);
  unsigned* hist1 = (unsigned*)(ws + zOff);
  unsigned* hist2 = hist1 + 3 * 256;
  unsigned* cnt   = hist2 + 3 * 256;
  unsigned* meta  = (unsigned*)(ws + take(12 * 4));
  unsigned long long* candKey = (unsigned long long*)(ws + take((size_t)3 * CAP * 8));
  unsigned* candIdx = (unsigned*)(ws + take((size_t)3 * CAP * 4));
  uint2* topk = (uint2*)(ws + take((size_t)3 * KCAND * 8));

  hipMemsetAsync(ws + zOff, 0, (3 * 256 + 3 * 256 + 3) * 4, stream);

  // encoder (fp64)
  conv1_k<<<N1 / 256, 256, 0, stream>>>(x, c1w, c1b, f1d);
  conv2_k<<<N2 / 256, 256, 0, stream>>>(f1d, c2w, c2b, f2d);
  conv3_k<<<dim3(N3 / 256, 4), 256, 0, stream>>>(f2d, c3w, c3b, f3d);
  // FPN top-down (fp64 + fp32 copies)
  p3_k<<<N3 / 256, 256, 0, stream>>>(f3d, l3w, l3b, p3d, p3f, s3);
  p2_k<<<N2 / 256, 256, 0, stream>>>(f2d, l2w, l2b, p3d, p2d, p2f, s2);
  p1_k<<<N1 / 256, 256, 0, stream>>>(f1d, l1w, l1b, p2d, p1f, s1);

  // selection (batched across 3 levels)
  hist1_k<<<dim3(64, 3), 256, 0, stream>>>(s1, s2, s3, hist1);
  pick1_k<<<1, 64, 0, stream>>>(hist1, meta);
  hist2_k<<<dim3(64, 3), 256, 0, stream>>>(s1, s2, s3, meta, hist2);
  pick2_k<<<1, 64, 0, stream>>>(hist2, meta);
  compact_k<<<dim3(112, 3), 256, 0, stream>>>(s1, s2, s3, meta, candKey, candIdx, cnt);
  sort_k<<<3, 1024, 0, stream>>>(candKey, candIdx, cnt, topk);
  mlp_k<<<dim3(KCAND, 3), 64, 0, stream>>>(topk, p1f, p2f, p3f, w1, b1, w2, b2, out);
}

// Round 4
// 631.950 us; speedup vs baseline: 3.8098x; 1.5122x over previous
//
#include <hip/hip_runtime.h>
#include <hip/hip_bf16.h>
#include <cstdint>
#include <cstddef>

// ---------------- sizes ----------------
#define N1 442368   // 48*96*96 spatial (f1, p1)
#define N2 55296    // 24*48*48 spatial (f2, p2)
#define N3 6912     // 12*24*24 spatial (f3, p3)

#define KCAND 512
#define CAP   4096

// ---------------- helpers ----------------
__device__ __forceinline__ unsigned long long f2key64(double f) {
  unsigned long long b = (unsigned long long)__double_as_longlong(f);
  return (b & 0x8000000000000000ULL) ? ~b : (b | 0x8000000000000000ULL);
}
__device__ __forceinline__ unsigned f2key32(float f) {
  unsigned b = __float_as_uint(f);
  return (b & 0x80000000u) ? ~b : (b | 0x80000000u);
}

// ---------------- conv1: 1->16ch, in 96x192x192, out 48x96x96 (fp64 acc) ----------------
__global__ void conv1_k(const float* __restrict__ x, const float* __restrict__ w,
                        const float* __restrict__ b, double* __restrict__ f1) {
  __shared__ float ws[16 * 27];
  for (int i = threadIdx.x; i < 16 * 27; i += blockDim.x) ws[i] = w[i];
  __syncthreads();
  int v = blockIdx.x * blockDim.x + threadIdx.x;
  if (v >= N1) return;
  int z = v / (96 * 96); int r = v % (96 * 96); int y = r / 96; int xo = r % 96;
  double acc[16];
#pragma unroll
  for (int c = 0; c < 16; c++) acc[c] = (double)b[c];
  for (int dz = 0; dz < 3; dz++) {
    int zi = 2 * z + dz; if (zi >= 96) break;
    for (int dy = 0; dy < 3; dy++) {
      int yi = 2 * y + dy; if (yi >= 192) break;
      for (int dx = 0; dx < 3; dx++) {
        int xi = 2 * xo + dx; if (xi >= 192) break;
        double vv = (double)x[(zi * 192 + yi) * 192 + xi];
        int t = (dz * 3 + dy) * 3 + dx;
#pragma unroll
        for (int c = 0; c < 16; c++) acc[c] = fma(vv, (double)ws[c * 27 + t], acc[c]);
      }
    }
  }
#pragma unroll
  for (int c = 0; c < 16; c++) f1[(size_t)c * N1 + v] = fmax(acc[c], 0.0);
}

// ---------------- conv2: 16->32ch, out 24x48x48; gridDim.y=4 groups of 8 (fp64) ----------------
__global__ __launch_bounds__(256) void conv2_k(const double* __restrict__ f1, const float* __restrict__ w,
                                               const float* __restrict__ b, double* __restrict__ f2) {
  __shared__ float ws[8 * 16 * 27];
  int g = blockIdx.y;  // 8 output channels per group
  for (int i = threadIdx.x; i < 8 * 16 * 27; i += blockDim.x) ws[i] = w[g * (8 * 16 * 27) + i];
  __syncthreads();
  int v = blockIdx.x * blockDim.x + threadIdx.x;
  if (v >= N2) return;
  int z = v / (48 * 48); int r = v % (48 * 48); int y = r / 48; int xo = r % 48;
  double acc[8];
#pragma unroll
  for (int c = 0; c < 8; c++) acc[c] = (double)b[g * 8 + c];
  for (int ci = 0; ci < 16; ci++) {
    const double* fp = f1 + (size_t)ci * N1;
    for (int dz = 0; dz < 3; dz++) {
      int zi = 2 * z + dz; if (zi >= 48) break;
      for (int dy = 0; dy < 3; dy++) {
        int yi = 2 * y + dy; if (yi >= 96) break;
        for (int dx = 0; dx < 3; dx++) {
          int xi = 2 * xo + dx; if (xi >= 96) break;
          double vv = fp[(zi * 96 + yi) * 96 + xi];
          int t = (dz * 3 + dy) * 3 + dx;
#pragma unroll
          for (int c = 0; c < 8; c++) acc[c] = fma(vv, (double)ws[(c * 16 + ci) * 27 + t], acc[c]);
        }
      }
    }
  }
#pragma unroll
  for (int c = 0; c < 8; c++) f2[(size_t)(g * 8 + c) * N2 + v] = fmax(acc[c], 0.0);
}

// ---------------- conv3: 32->64ch, out 12x24x24; gridDim.y=16 groups of 4 (fp64) ----------------
__global__ __launch_bounds__(256) void conv3_k(const double* __restrict__ f2, const float* __restrict__ w,
                                               const float* __restrict__ b, double* __restrict__ f3) {
  __shared__ float ws[4 * 32 * 27];
  int g = blockIdx.y;  // 4 output channels per group
  for (int i = threadIdx.x; i < 4 * 32 * 27; i += blockDim.x) ws[i] = w[g * (4 * 32 * 27) + i];
  __syncthreads();
  int v = blockIdx.x * blockDim.x + threadIdx.x;
  if (v >= N3) return;
  int z = v / (24 * 24); int r = v % (24 * 24); int y = r / 24; int xo = r % 24;
  double acc[4];
#pragma unroll
  for (int c = 0; c < 4; c++) acc[c] = (double)b[g * 4 + c];
  for (int ci = 0; ci < 32; ci++) {
    const double* fp = f2 + (size_t)ci * N2;
    for (int dz = 0; dz < 3; dz++) {
      int zi = 2 * z + dz; if (zi >= 24) break;
      for (int dy = 0; dy < 3; dy++) {
        int yi = 2 * y + dy; if (yi >= 48) break;
        for (int dx = 0; dx < 3; dx++) {
          int xi = 2 * xo + dx; if (xi >= 48) break;
          double vv = fp[(zi * 48 + yi) * 48 + xi];
          int t = (dz * 3 + dy) * 3 + dx;
#pragma unroll
          for (int c = 0; c < 4; c++) acc[c] = fma(vv, (double)ws[(c * 32 + ci) * 27 + t], acc[c]);
        }
      }
    }
  }
#pragma unroll
  for (int c = 0; c < 4; c++) f3[(size_t)(g * 4 + c) * N3 + v] = fmax(acc[c], 0.0);
}

// ---------------- p3 = l3(f3); score3 (fp64; also fp32 copy for cubes) ----------------
__global__ void p3_k(const double* __restrict__ f3, const float* __restrict__ w,
                     const float* __restrict__ b, double* __restrict__ p3d,
                     float* __restrict__ p3f, double* __restrict__ s3) {
  __shared__ float ws[32 * 64];
  for (int i = threadIdx.x; i < 32 * 64; i += blockDim.x) ws[i] = w[i];
  __syncthreads();
  int v = blockIdx.x * blockDim.x + threadIdx.x;
  if (v >= N3) return;
  double acc[32];
#pragma unroll
  for (int c = 0; c < 32; c++) acc[c] = (double)b[c];
  for (int ci = 0; ci < 64; ci++) {
    double vv = f3[(size_t)ci * N3 + v];
#pragma unroll
    for (int c = 0; c < 32; c++) acc[c] = fma(vv, (double)ws[c * 64 + ci], acc[c]);
  }
  double m = -1e300;
#pragma unroll
  for (int c = 0; c < 32; c++) {
    p3d[(size_t)c * N3 + v] = acc[c];
    p3f[(size_t)c * N3 + v] = (float)acc[c];
    m = fmax(m, acc[c]);
  }
  s3[v] = m;
}

// ---------------- p2 = l2(f2) + up2(p3); score2 ----------------
__global__ void p2_k(const double* __restrict__ f2, const float* __restrict__ w,
                     const float* __restrict__ b, const double* __restrict__ p3d,
                     double* __restrict__ p2d, float* __restrict__ p2f, double* __restrict__ s2) {
  __shared__ float ws[32 * 32];
  for (int i = threadIdx.x; i < 32 * 32; i += blockDim.x) ws[i] = w[i];
  __syncthreads();
  int v = blockIdx.x * blockDim.x + threadIdx.x;
  if (v >= N2) return;
  int z = v / (48 * 48); int r = v % (48 * 48); int y = r / 48; int xo = r % 48;
  int up = ((z >> 1) * 24 + (y >> 1)) * 24 + (xo >> 1);
  double acc[32];
#pragma unroll
  for (int c = 0; c < 32; c++) acc[c] = (double)b[c];
  for (int ci = 0; ci < 32; ci++) {
    double vv = f2[(size_t)ci * N2 + v];
#pragma unroll
    for (int c = 0; c < 32; c++) acc[c] = fma(vv, (double)ws[c * 32 + ci], acc[c]);
  }
  double m = -1e300;
#pragma unroll
  for (int c = 0; c < 32; c++) {
    double o = acc[c] + p3d[(size_t)c * N3 + up];
    p2d[(size_t)c * N2 + v] = o;
    p2f[(size_t)c * N2 + v] = (float)o;
    m = fmax(m, o);
  }
  s2[v] = m;
}

// ---------------- p1 = l1(f1) + up2(p2); score1 (fp32 p1 only + fp64 score) ----------------
__global__ void p1_k(const double* __restrict__ f1, const float* __restrict__ w,
                     const float* __restrict__ b, const double* __restrict__ p2d,
                     float* __restrict__ p1f, double* __restrict__ s1) {
  __shared__ float ws[32 * 16];
  for (int i = threadIdx.x; i < 32 * 16; i += blockDim.x) ws[i] = w[i];
  __syncthreads();
  int v = blockIdx.x * blockDim.x + threadIdx.x;
  if (v >= N1) return;
  int z = v / (96 * 96); int r = v % (96 * 96); int y = r / 96; int xo = r % 96;
  int up = ((z >> 1) * 48 + (y >> 1)) * 48 + (xo >> 1);
  double acc[32];
#pragma unroll
  for (int c = 0; c < 32; c++) acc[c] = (double)b[c];
  for (int ci = 0; ci < 16; ci++) {
    double vv = f1[(size_t)ci * N1 + v];
#pragma unroll
    for (int c = 0; c < 32; c++) acc[c] = fma(vv, (double)ws[c * 16 + ci], acc[c]);
  }
  double m = -1e300;
#pragma unroll
  for (int c = 0; c < 32; c++) {
    double o = acc[c] + p2d[(size_t)c * N2 + up];
    p1f[(size_t)c * N1 + v] = (float)o;
    m = fmax(m, o);
  }
  s1[v] = m;
}

// ---------------- selection: two-pass 256-bin radix over fp32 key, batched over levels ----------------
__global__ void hist1_k(const double* __restrict__ s1, const double* __restrict__ s2,
                        const double* __restrict__ s3, unsigned* __restrict__ hist) {
  int L = blockIdx.y;
  const double* s = L == 0 ? s1 : (L == 1 ? s2 : s3);
  int n = L == 0 ? N1 : (L == 1 ? N2 : N3);
  unsigned* hg = hist + L * 256;
  __shared__ unsigned h[256];
  h[threadIdx.x] = 0;
  __syncthreads();
  for (int i = blockIdx.x * 256 + threadIdx.x; i < n; i += gridDim.x * 256)
    atomicAdd(&h[f2key32((float)s[i]) >> 24], 1u);
  __syncthreads();
  unsigned v = h[threadIdx.x];
  if (v) atomicAdd(&hg[threadIdx.x], v);
}

__global__ void pick1_k(const unsigned* __restrict__ hist, unsigned* __restrict__ meta) {
  int L = threadIdx.x;
  if (L >= 3) return;
  const unsigned* hg = hist + L * 256;
  unsigned run = 0; int b = 0;
  for (int i = 255; i >= 0; i--) {
    unsigned c = hg[i];
    if (run + c >= (unsigned)KCAND) { b = i; break; }
    run += c;
  }
  meta[L * 4 + 0] = (unsigned)b;
  meta[L * 4 + 1] = run;
}

__global__ void hist2_k(const double* __restrict__ s1, const double* __restrict__ s2,
                        const double* __restrict__ s3, const unsigned* __restrict__ meta,
                        unsigned* __restrict__ hist2) {
  int L = blockIdx.y;
  const double* s = L == 0 ? s1 : (L == 1 ? s2 : s3);
  int n = L == 0 ? N1 : (L == 1 ? N2 : N3);
  unsigned b1 = meta[L * 4 + 0];
  unsigned* hg = hist2 + L * 256;
  __shared__ unsigned h[256];
  h[threadIdx.x] = 0;
  __syncthreads();
  for (int i = blockIdx.x * 256 + threadIdx.x; i < n; i += gridDim.x * 256) {
    unsigned k = f2key32((float)s[i]);
    if ((k >> 24) == b1) atomicAdd(&h[(k >> 16) & 255u], 1u);
  }
  __syncthreads();
  unsigned v = h[threadIdx.x];
  if (v) atomicAdd(&hg[threadIdx.x], v);
}

__global__ void pick2_k(const unsigned* __restrict__ hist2, unsigned* __restrict__ meta) {
  int L = threadIdx.x;
  if (L >= 3) return;
  const unsigned* hg = hist2 + L * 256;
  unsigned b1 = meta[L * 4 + 0];
  unsigned run = meta[L * 4 + 1];
  unsigned b2 = 0;
  for (int i = 255; i >= 0; i--) {
    run += hg[i];
    if (run >= (unsigned)KCAND) { b2 = (unsigned)i; break; }
  }
  meta[L * 4 + 2] = (b1 << 24) | (b2 << 16);
}

__global__ void compact_k(const double* __restrict__ s1, const double* __restrict__ s2,
                          const double* __restrict__ s3, const unsigned* __restrict__ meta,
                          unsigned long long* __restrict__ ck, unsigned* __restrict__ cidx,
                          unsigned* __restrict__ cnt) {
  int L = blockIdx.y;
  const double* s = L == 0 ? s1 : (L == 1 ? s2 : s3);
  int n = L == 0 ? N1 : (L == 1 ? N2 : N3);
  unsigned T = meta[L * 4 + 2];
  for (int i = blockIdx.x * 256 + threadIdx.x; i < n; i += gridDim.x * 256) {
    double v = s[i];
    if (f2key32((float)v) >= T) {
      unsigned pos = atomicAdd(&cnt[L], 1u);
      if (pos < (unsigned)CAP) {
        ck[(size_t)L * CAP + pos] = f2key64(v);
        cidx[(size_t)L * CAP + pos] = (unsigned)i;
      }
    }
  }
}

// one-block-per-level bitonic sort: (fp64 score desc, idx asc); emits top-512 (idx, valid)
__global__ void sort_k(const unsigned long long* __restrict__ ckA, const unsigned* __restrict__ cidxA,
                       const unsigned* __restrict__ cnt, uint2* __restrict__ topkA) {
  __shared__ unsigned long long k_[CAP];
  __shared__ unsigned x_[CAP];
  int L = blockIdx.x;
  const unsigned long long* ck = ckA + (size_t)L * CAP;
  const unsigned* cidx = cidxA + (size_t)L * CAP;
  uint2* topk = topkA + (size_t)L * KCAND;
  int t = threadIdx.x;
  unsigned m = cnt[L]; if (m > (unsigned)CAP) m = CAP;
  int sz = 512; while (sz < (int)m) sz <<= 1;   // m >= 512 guaranteed
  for (int i = t; i < sz; i += 1024) {
    if (i < (int)m) { k_[i] = ck[i]; x_[i] = cidx[i]; }
    else            { k_[i] = 0ULL;  x_[i] = 0xFFFFFFFFu; }
  }
  __syncthreads();
  for (int kk = 2; kk <= sz; kk <<= 1) {
    for (int j = kk >> 1; j > 0; j >>= 1) {
      for (int i = t; i < sz; i += 1024) {
        int l = i ^ j;
        if (l > i) {
          unsigned long long ka = k_[i], kb = k_[l];
          unsigned ia = x_[i], ib = x_[l];
          bool b_first = (kb > ka) || (kb == ka && ib < ia);  // b ranks before a?
          bool up = (i & kk) == 0;                            // descending region
          if (up == b_first) { k_[i] = kb; x_[i] = ib; k_[l] = ka; x_[l] = ia; }
        }
      }
      __syncthreads();
    }
  }
  if (t < KCAND) {
    unsigned long long key = k_[t];
    unsigned long long bb = (key >> 63) ? (key & 0x7FFFFFFFFFFFFFFFULL) : ~key;
    double sc = __longlong_as_double((long long)bb);
    topk[t] = make_uint2(x_[t], sc > 0.5 ? 1u : 0u);
  }
}

// ---------------- per-candidate cube stats + MLP (fp64 math, fp32 data); batched levels ----------------
__global__ __launch_bounds__(64) void mlp_k(const uint2* __restrict__ topkA,
                                            const float* __restrict__ pa, const float* __restrict__ pb,
                                            const float* __restrict__ pc_,
                                            const float* __restrict__ w1, const float* __restrict__ b1,
                                            const float* __restrict__ w2, const float* __restrict__ b2,
                                            float* __restrict__ out) {
  __shared__ double lhi[64];
  int L = blockIdx.y;
  int s = blockIdx.x;
  const float* p = L == 0 ? pa : (L == 1 ? pb : pc_);
  int D = 48 >> L, H = 96 >> L, W = 96 >> L;
  uint2 e = topkA[(size_t)L * KCAND + s];
  unsigned idx = e.x;
  double valid = e.y ? 1.0 : 0.0;
  int HW = H * W;
  int z = (int)(idx / (unsigned)HW);
  int r = (int)(idx % (unsigned)HW);
  int y = r / W; int x = r % W;
  int zs = min(max(z - 2, 0), D - 4);
  int ys = min(max(y - 2, 0), H - 4);
  int xs = min(max(x - 2, 0), W - 4);
  int t = threadIdx.x;
  int c = t & 31, h = t >> 5;
  const float* pc = p + (size_t)c * D * HW;
  double sum = 0.0, ss = 0.0;
  for (int i = 0; i < 32; i++) {
    int vv = h * 32 + i;
    int dz = vv >> 4, dy = (vv >> 2) & 3, dx = vv & 3;
    double val = (double)pc[(zs + dz) * HW + (ys + dy) * W + (xs + dx)];
    sum += val; ss = fma(val, val, ss);
  }
  sum += __shfl_xor(sum, 32);
  ss  += __shfl_xor(ss, 32);
  if (h == 0) {
    double mean = sum * (1.0 / 64.0);
    double var = ss * (1.0 / 64.0) - mean * mean;
    lhi[c] = mean;
    lhi[32 + c] = sqrt(var + 1e-6);
  }
  __syncthreads();
  double h0 = (double)b1[t], h1 = (double)b1[t + 64];
  for (int i = 0; i < 64; i++) {
    double li = lhi[i];
    h0 = fma(li, (double)w1[i * 128 + t], h0);
    h1 = fma(li, (double)w1[i * 128 + t + 64], h1);
  }
  h0 = fmax(h0, 0.0); h1 = fmax(h1, 0.0);
  double o0 = h0 * (double)w2[t * 2 + 0] + h1 * (double)w2[(t + 64) * 2 + 0];
  double o1 = h0 * (double)w2[t * 2 + 1] + h1 * (double)w2[(t + 64) * 2 + 1];
  for (int o = 1; o < 64; o <<= 1) { o0 += __shfl_xor(o0, o); o1 += __shfl_xor(o1, o); }
  if (t == 0) {
    out[((size_t)L * KCAND + s) * 2 + 0] = (float)((o0 + (double)b2[0]) * valid);
    out[((size_t)L * KCAND + s) * 2 + 1] = (float)((o1 + (double)b2[1]) * valid);
  }
}

// ---------------- launch ----------------
extern "C" void kernel_launch(void* const* d_in, const int* in_sizes, int n_in,
                              void* d_out, int out_size, void* d_ws, size_t ws_size,
                              hipStream_t stream) {
  const float* x   = (const float*)d_in[0];
  const float* c1w = (const float*)d_in[1];  const float* c1b = (const float*)d_in[2];
  const float* c2w = (const float*)d_in[3];  const float* c2b = (const float*)d_in[4];
  const float* c3w = (const float*)d_in[5];  const float* c3b = (const float*)d_in[6];
  const float* l1w = (const float*)d_in[7];  const float* l1b = (const float*)d_in[8];
  const float* l2w = (const float*)d_in[9];  const float* l2b = (const float*)d_in[10];
  const float* l3w = (const float*)d_in[11]; const float* l3b = (const float*)d_in[12];
  const float* w1  = (const float*)d_in[13]; const float* b1  = (const float*)d_in[14];
  const float* w2  = (const float*)d_in[15]; const float* b2  = (const float*)d_in[16];
  float* out = (float*)d_out;

  char* ws = (char*)d_ws;
  size_t off = 0;
  auto take = [&](size_t bytes) { size_t o = off; off = (off + bytes + 255) & ~(size_t)255; return o; };
  double* f1d = (double*)(ws + take((size_t)16 * N1 * 8));
  double* f2d = (double*)(ws + take((size_t)32 * N2 * 8));
  double* f3d = (double*)(ws + take((size_t)64 * N3 * 8));
  float*  p1f = (float*) (ws + take((size_t)32 * N1 * 4));
  double* p2d = (double*)(ws + take((size_t)32 * N2 * 8));
  float*  p2f = (float*) (ws + take((size_t)32 * N2 * 4));
  double* p3d = (double*)(ws + take((size_t)32 * N3 * 8));
  float*  p3f = (float*) (ws + take((size_t)32 * N3 * 4));
  double* s1 = (double*)(ws + take((size_t)N1 * 8));
  double* s2 = (double*)(ws + take((size_t)N2 * 8));
  double* s3 = (double*)(ws + take((size_t)N3 * 8));
  // selection scratch: hist1[3*256] hist2[3*256] cnt[3] (zeroed) + meta[12] (always written)
  size_t zOff = take((3 * 256 + 3 * 256 + 3) * 4);
  unsigned* hist1 = (unsigned*)(ws + zOff);
  unsigned* hist2 = hist1 + 3 * 256;
  unsigned* cnt   = hist2 + 3 * 256;
  unsigned* meta  = (unsigned*)(ws + take(12 * 4));
  unsigned long long* candKey = (unsigned long long*)(ws + take((size_t)3 * CAP * 8));
  unsigned* candIdx = (unsigned*)(ws + take((size_t)3 * CAP * 4));
  uint2* topk = (uint2*)(ws + take((size_t)3 * KCAND * 8));

  hipMemsetAsync(ws + zOff, 0, (3 * 256 + 3 * 256 + 3) * 4, stream);

  // encoder (fp64)
  conv1_k<<<N1 / 256, 256, 0, stream>>>(x, c1w, c1b, f1d);
  conv2_k<<<dim3(N2 / 256, 4), 256, 0, stream>>>(f1d, c2w, c2b, f2d);
  conv3_k<<<dim3(N3 / 256, 16), 256, 0, stream>>>(f2d, c3w, c3b, f3d);
  // FPN top-down (fp64 + fp32 copies)
  p3_k<<<N3 / 256, 256, 0, stream>>>(f3d, l3w, l3b, p3d, p3f, s3);
  p2_k<<<N2 / 256, 256, 0, stream>>>(f2d, l2w, l2b, p3d, p2d, p2f, s2);
  p1_k<<<N1 / 256, 256, 0, stream>>>(f1d, l1w, l1b, p2d, p1f, s1);

  // selection (batched across 3 levels)
  hist1_k<<<dim3(64, 3), 256, 0, stream>>>(s1, s2, s3, hist1);
  pick1_k<<<1, 64, 0, stream>>>(hist1, meta);
  hist2_k<<<dim3(64, 3), 256, 0, stream>>>(s1, s2, s3, meta, hist2);
  pick2_k<<<1, 64, 0, stream>>>(hist2, meta);
  compact_k<<<dim3(112, 3), 256, 0, stream>>>(s1, s2, s3, meta, candKey, candIdx, cnt);
  sort_k<<<3, 1024, 0, stream>>>(candKey, candIdx, cnt, topk);
  mlp_k<<<dim3(KCAND, 3), 64, 0, stream>>>(topk, p1f, p2f, p3f, w1, b1, w2, b2, out);
}

// Round 5
// 481.671 us; speedup vs baseline: 4.9984x; 1.3120x over previous
//
#include <hip/hip_runtime.h>
#include <hip/hip_bf16.h>
#include <cstdint>
#include <cstddef>

// ---------------- sizes ----------------
#define N1 442368   // 48*96*96 spatial (p1, s1)
#define N2 55296    // 24*48*48 spatial (p2, s2)
#define N3 6912     // 12*24*24 spatial (p3, s3)

// padded fp64 feature layouts (pad at high edge so conv taps are branch-free)
#define PZ1 9409    // 97*97
#define PN1 461041  // 49*97*97
#define PV1 461041
#define PZ2 2401    // 49*49
#define PN2 60025   // 25*49*49
#define PV2 60025

#define KCAND 512
#define CAP   4096

// ---------------- helpers ----------------
__device__ __forceinline__ unsigned long long f2key64(double f) {
  unsigned long long b = (unsigned long long)__double_as_longlong(f);
  return (b & 0x8000000000000000ULL) ? ~b : (b | 0x8000000000000000ULL);
}
__device__ __forceinline__ unsigned f2key32(float f) {
  unsigned b = __float_as_uint(f);
  return (b & 0x80000000u) ? ~b : (b | 0x80000000u);
}

// ---------------- conv1: 1->16ch, in 96x192x192, out padded [16][49][97][97] ----------------
__global__ __launch_bounds__(256) void conv1_k(const float* __restrict__ x, const float* __restrict__ w,
                                               const float* __restrict__ b, double* __restrict__ f1) {
  __shared__ __align__(16) float wsT[27 * 16];  // [t][c]
  for (int i = threadIdx.x; i < 27 * 16; i += 256) {
    int t = i >> 4, c = i & 15;
    wsT[i] = w[c * 27 + t];
  }
  __syncthreads();
  int v = blockIdx.x * 256 + threadIdx.x;
  if (v >= PV1) return;
  int z = v / PZ1; int r = v % PZ1; int y = r / 97; int xo = r % 97;
  if (z >= 48 || y >= 96 || xo >= 96) {
#pragma unroll
    for (int c = 0; c < 16; c++) f1[(size_t)c * PN1 + v] = 0.0;
    return;
  }
  float val[27];
#pragma unroll
  for (int dz = 0; dz < 3; dz++)
#pragma unroll
    for (int dy = 0; dy < 3; dy++)
#pragma unroll
      for (int dx = 0; dx < 3; dx++) {
        int zi = 2 * z + dz, yi = 2 * y + dy, xi = 2 * xo + dx;
        bool ok = (zi < 96) & (yi < 192) & (xi < 192);
        int zc = min(zi, 95), yc = min(yi, 191), xc = min(xi, 191);
        float t = x[(zc * 192 + yc) * 192 + xc];
        val[(dz * 3 + dy) * 3 + dx] = ok ? t : 0.0f;
      }
  double acc[16];
#pragma unroll
  for (int c = 0; c < 16; c++) acc[c] = (double)b[c];
  const float4* wsv = (const float4*)wsT;
#pragma unroll
  for (int t = 0; t < 27; t++) {
    double vv = (double)val[t];
#pragma unroll
    for (int j = 0; j < 4; j++) {
      float4 wq = wsv[t * 4 + j];
      acc[4 * j + 0] = fma(vv, (double)wq.x, acc[4 * j + 0]);
      acc[4 * j + 1] = fma(vv, (double)wq.y, acc[4 * j + 1]);
      acc[4 * j + 2] = fma(vv, (double)wq.z, acc[4 * j + 2]);
      acc[4 * j + 3] = fma(vv, (double)wq.w, acc[4 * j + 3]);
    }
  }
#pragma unroll
  for (int c = 0; c < 16; c++) f1[(size_t)c * PN1 + v] = fmax(acc[c], 0.0);
}

// ---------------- conv2: 16->32ch, out padded [32][25][49][49]; gridDim.y=4 groups of 8 ----------------
__global__ __launch_bounds__(256) void conv2_k(const double* __restrict__ f1, const float* __restrict__ w,
                                               const float* __restrict__ b, double* __restrict__ f2) {
  __shared__ __align__(16) float wsT[16 * 27 * 8];  // [ci][t][c]
  int g = blockIdx.y;
  for (int i = threadIdx.x; i < 16 * 27 * 8; i += 256) {
    int ci = i / 216, rem = i % 216, t = rem >> 3, c = rem & 7;
    wsT[i] = w[((size_t)(g * 8 + c) * 16 + ci) * 27 + t];
  }
  __syncthreads();
  int v = blockIdx.x * 256 + threadIdx.x;
  if (v >= PV2) return;
  int z = v / PZ2; int r = v % PZ2; int y = r / 49; int xo = r % 49;
  if (z >= 24 || y >= 48 || xo >= 48) {
#pragma unroll
    for (int c = 0; c < 8; c++) f2[(size_t)(g * 8 + c) * PN2 + v] = 0.0;
    return;
  }
  double acc[8];
#pragma unroll
  for (int c = 0; c < 8; c++) acc[c] = (double)b[g * 8 + c];
  const double* base = f1 + (size_t)(2 * z) * PZ1 + (2 * y) * 97 + 2 * xo;
  const float4* wsv = (const float4*)wsT;
  for (int ci = 0; ci < 16; ci++) {
    const double* fp = base + (size_t)ci * PN1;
    double vals[27];
#pragma unroll
    for (int dz = 0; dz < 3; dz++)
#pragma unroll
      for (int dy = 0; dy < 3; dy++)
#pragma unroll
        for (int dx = 0; dx < 3; dx++)
          vals[(dz * 3 + dy) * 3 + dx] = fp[dz * PZ1 + dy * 97 + dx];
#pragma unroll
    for (int t = 0; t < 27; t++) {
      double vv = vals[t];
      float4 wa = wsv[(ci * 27 + t) * 2 + 0];
      float4 wb = wsv[(ci * 27 + t) * 2 + 1];
      acc[0] = fma(vv, (double)wa.x, acc[0]);
      acc[1] = fma(vv, (double)wa.y, acc[1]);
      acc[2] = fma(vv, (double)wa.z, acc[2]);
      acc[3] = fma(vv, (double)wa.w, acc[3]);
      acc[4] = fma(vv, (double)wb.x, acc[4]);
      acc[5] = fma(vv, (double)wb.y, acc[5]);
      acc[6] = fma(vv, (double)wb.z, acc[6]);
      acc[7] = fma(vv, (double)wb.w, acc[7]);
    }
  }
#pragma unroll
  for (int c = 0; c < 8; c++) f2[(size_t)(g * 8 + c) * PN2 + v] = fmax(acc[c], 0.0);
}

// ---------------- conv3: 32->64ch, out [64][6912]; gridDim.y=16 groups of 4 ----------------
__global__ __launch_bounds__(256) void conv3_k(const double* __restrict__ f2, const float* __restrict__ w,
                                               const float* __restrict__ b, double* __restrict__ f3) {
  __shared__ __align__(16) float wsT[32 * 27 * 4];  // [ci][t][c]
  int g = blockIdx.y;
  for (int i = threadIdx.x; i < 32 * 27 * 4; i += 256) {
    int ci = i / 108, rem = i % 108, t = rem >> 2, c = rem & 3;
    wsT[i] = w[((size_t)(g * 4 + c) * 32 + ci) * 27 + t];
  }
  __syncthreads();
  int v = blockIdx.x * 256 + threadIdx.x;
  if (v >= N3) return;
  int z = v / 576; int r = v % 576; int y = r / 24; int xo = r % 24;
  double acc[4];
#pragma unroll
  for (int c = 0; c < 4; c++) acc[c] = (double)b[g * 4 + c];
  const double* base = f2 + (size_t)(2 * z) * PZ2 + (2 * y) * 49 + 2 * xo;
  const float4* wsv = (const float4*)wsT;
  for (int ci = 0; ci < 32; ci++) {
    const double* fp = base + (size_t)ci * PN2;
    double vals[27];
#pragma unroll
    for (int dz = 0; dz < 3; dz++)
#pragma unroll
      for (int dy = 0; dy < 3; dy++)
#pragma unroll
        for (int dx = 0; dx < 3; dx++)
          vals[(dz * 3 + dy) * 3 + dx] = fp[dz * PZ2 + dy * 49 + dx];
#pragma unroll
    for (int t = 0; t < 27; t++) {
      double vv = vals[t];
      float4 wq = wsv[ci * 27 + t];
      acc[0] = fma(vv, (double)wq.x, acc[0]);
      acc[1] = fma(vv, (double)wq.y, acc[1]);
      acc[2] = fma(vv, (double)wq.z, acc[2]);
      acc[3] = fma(vv, (double)wq.w, acc[3]);
    }
  }
#pragma unroll
  for (int c = 0; c < 4; c++) f3[(size_t)(g * 4 + c) * N3 + v] = fmax(acc[c], 0.0);
}

// ---------------- p3 = l3(f3); score3 ----------------
__global__ __launch_bounds__(256) void p3_k(const double* __restrict__ f3, const float* __restrict__ w,
                                            const float* __restrict__ b, double* __restrict__ p3d,
                                            float* __restrict__ p3f, double* __restrict__ s3) {
  __shared__ __align__(16) float wsT[64 * 32];  // [ci][c]
  for (int i = threadIdx.x; i < 64 * 32; i += 256) {
    int ci = i >> 5, c = i & 31;
    wsT[i] = w[c * 64 + ci];
  }
  __syncthreads();
  int v = blockIdx.x * 256 + threadIdx.x;
  if (v >= N3) return;
  double acc[32];
#pragma unroll
  for (int c = 0; c < 32; c++) acc[c] = (double)b[c];
  const float4* wsv = (const float4*)wsT;
  for (int ci = 0; ci < 64; ci++) {
    double vv = f3[(size_t)ci * N3 + v];
#pragma unroll
    for (int j = 0; j < 8; j++) {
      float4 wq = wsv[ci * 8 + j];
      acc[4 * j + 0] = fma(vv, (double)wq.x, acc[4 * j + 0]);
      acc[4 * j + 1] = fma(vv, (double)wq.y, acc[4 * j + 1]);
      acc[4 * j + 2] = fma(vv, (double)wq.z, acc[4 * j + 2]);
      acc[4 * j + 3] = fma(vv, (double)wq.w, acc[4 * j + 3]);
    }
  }
  double m = -1e300;
#pragma unroll
  for (int c = 0; c < 32; c++) {
    p3d[(size_t)c * N3 + v] = acc[c];
    p3f[(size_t)c * N3 + v] = (float)acc[c];
    m = fmax(m, acc[c]);
  }
  s3[v] = m;
}

// ---------------- p2 = l2(f2) + up2(p3); score2 ----------------
__global__ __launch_bounds__(256) void p2_k(const double* __restrict__ f2, const float* __restrict__ w,
                                            const float* __restrict__ b, const double* __restrict__ p3d,
                                            double* __restrict__ p2d, float* __restrict__ p2f, double* __restrict__ s2) {
  __shared__ __align__(16) float wsT[32 * 32];  // [ci][c]
  for (int i = threadIdx.x; i < 32 * 32; i += 256) {
    int ci = i >> 5, c = i & 31;
    wsT[i] = w[c * 32 + ci];
  }
  __syncthreads();
  int v = blockIdx.x * 256 + threadIdx.x;
  if (v >= N2) return;
  int z = v / (48 * 48); int r = v % (48 * 48); int y = r / 48; int xo = r % 48;
  int pidx = z * PZ2 + y * 49 + xo;  // padded f2 voxel
  int up = ((z >> 1) * 24 + (y >> 1)) * 24 + (xo >> 1);
  double acc[32];
#pragma unroll
  for (int c = 0; c < 32; c++) acc[c] = (double)b[c];
  const float4* wsv = (const float4*)wsT;
  for (int ci = 0; ci < 32; ci++) {
    double vv = f2[(size_t)ci * PN2 + pidx];
#pragma unroll
    for (int j = 0; j < 8; j++) {
      float4 wq = wsv[ci * 8 + j];
      acc[4 * j + 0] = fma(vv, (double)wq.x, acc[4 * j + 0]);
      acc[4 * j + 1] = fma(vv, (double)wq.y, acc[4 * j + 1]);
      acc[4 * j + 2] = fma(vv, (double)wq.z, acc[4 * j + 2]);
      acc[4 * j + 3] = fma(vv, (double)wq.w, acc[4 * j + 3]);
    }
  }
  double m = -1e300;
#pragma unroll
  for (int c = 0; c < 32; c++) {
    double o = acc[c] + p3d[(size_t)c * N3 + up];
    p2d[(size_t)c * N2 + v] = o;
    p2f[(size_t)c * N2 + v] = (float)o;
    m = fmax(m, o);
  }
  s2[v] = m;
}

// ---------------- p1 = l1(f1) + up2(p2); score1 ----------------
__global__ __launch_bounds__(256) void p1_k(const double* __restrict__ f1, const float* __restrict__ w,
                                            const float* __restrict__ b, const double* __restrict__ p2d,
                                            float* __restrict__ p1f, double* __restrict__ s1) {
  __shared__ __align__(16) float wsT[16 * 32];  // [ci][c]
  for (int i = threadIdx.x; i < 16 * 32; i += 256) {
    int ci = i >> 5, c = i & 31;
    wsT[i] = w[c * 16 + ci];
  }
  __syncthreads();
  int v = blockIdx.x * 256 + threadIdx.x;
  if (v >= N1) return;
  int z = v / (96 * 96); int r = v % (96 * 96); int y = r / 96; int xo = r % 96;
  int pidx = z * PZ1 + y * 97 + xo;  // padded f1 voxel
  int up = ((z >> 1) * 48 + (y >> 1)) * 48 + (xo >> 1);
  double acc[32];
#pragma unroll
  for (int c = 0; c < 32; c++) acc[c] = (double)b[c];
  const float4* wsv = (const float4*)wsT;
  for (int ci = 0; ci < 16; ci++) {
    double vv = f1[(size_t)ci * PN1 + pidx];
#pragma unroll
    for (int j = 0; j < 8; j++) {
      float4 wq = wsv[ci * 8 + j];
      acc[4 * j + 0] = fma(vv, (double)wq.x, acc[4 * j + 0]);
      acc[4 * j + 1] = fma(vv, (double)wq.y, acc[4 * j + 1]);
      acc[4 * j + 2] = fma(vv, (double)wq.z, acc[4 * j + 2]);
      acc[4 * j + 3] = fma(vv, (double)wq.w, acc[4 * j + 3]);
    }
  }
  double m = -1e300;
#pragma unroll
  for (int c = 0; c < 32; c++) {
    double o = acc[c] + p2d[(size_t)c * N2 + up];
    p1f[(size_t)c * N1 + v] = (float)o;
    m = fmax(m, o);
  }
  s1[v] = m;
}

// ---------------- selection: two-pass 256-bin radix over fp32 key, batched over levels ----------------
__global__ void hist1_k(const double* __restrict__ s1, const double* __restrict__ s2,
                        const double* __restrict__ s3, unsigned* __restrict__ hist) {
  int L = blockIdx.y;
  const double* s = L == 0 ? s1 : (L == 1 ? s2 : s3);
  int n = L == 0 ? N1 : (L == 1 ? N2 : N3);
  unsigned* hg = hist + L * 256;
  __shared__ unsigned h[256];
  h[threadIdx.x] = 0;
  __syncthreads();
  for (int i = blockIdx.x * 256 + threadIdx.x; i < n; i += gridDim.x * 256)
    atomicAdd(&h[f2key32((float)s[i]) >> 24], 1u);
  __syncthreads();
  unsigned v = h[threadIdx.x];
  if (v) atomicAdd(&hg[threadIdx.x], v);
}

__global__ void pick1_k(const unsigned* __restrict__ hist, unsigned* __restrict__ meta) {
  int L = threadIdx.x;
  if (L >= 3) return;
  const unsigned* hg = hist + L * 256;
  unsigned run = 0; int b = 0;
  for (int i = 255; i >= 0; i--) {
    unsigned c = hg[i];
    if (run + c >= (unsigned)KCAND) { b = i; break; }
    run += c;
  }
  meta[L * 4 + 0] = (unsigned)b;
  meta[L * 4 + 1] = run;
}

__global__ void hist2_k(const double* __restrict__ s1, const double* __restrict__ s2,
                        const double* __restrict__ s3, const unsigned* __restrict__ meta,
                        unsigned* __restrict__ hist2) {
  int L = blockIdx.y;
  const double* s = L == 0 ? s1 : (L == 1 ? s2 : s3);
  int n = L == 0 ? N1 : (L == 1 ? N2 : N3);
  unsigned b1 = meta[L * 4 + 0];
  unsigned* hg = hist2 + L * 256;
  __shared__ unsigned h[256];
  h[threadIdx.x] = 0;
  __syncthreads();
  for (int i = blockIdx.x * 256 + threadIdx.x; i < n; i += gridDim.x * 256) {
    unsigned k = f2key32((float)s[i]);
    if ((k >> 24) == b1) atomicAdd(&h[(k >> 16) & 255u], 1u);
  }
  __syncthreads();
  unsigned v = h[threadIdx.x];
  if (v) atomicAdd(&hg[threadIdx.x], v);
}

__global__ void pick2_k(const unsigned* __restrict__ hist2, unsigned* __restrict__ meta) {
  int L = threadIdx.x;
  if (L >= 3) return;
  const unsigned* hg = hist2 + L * 256;
  unsigned b1 = meta[L * 4 + 0];
  unsigned run = meta[L * 4 + 1];
  unsigned b2 = 0;
  for (int i = 255; i >= 0; i--) {
    run += hg[i];
    if (run >= (unsigned)KCAND) { b2 = (unsigned)i; break; }
  }
  meta[L * 4 + 2] = (b1 << 24) | (b2 << 16);
}

__global__ void compact_k(const double* __restrict__ s1, const double* __restrict__ s2,
                          const double* __restrict__ s3, const unsigned* __restrict__ meta,
                          unsigned long long* __restrict__ ck, unsigned* __restrict__ cidx,
                          unsigned* __restrict__ cnt) {
  int L = blockIdx.y;
  const double* s = L == 0 ? s1 : (L == 1 ? s2 : s3);
  int n = L == 0 ? N1 : (L == 1 ? N2 : N3);
  unsigned T = meta[L * 4 + 2];
  for (int i = blockIdx.x * 256 + threadIdx.x; i < n; i += gridDim.x * 256) {
    double v = s[i];
    if (f2key32((float)v) >= T) {
      unsigned pos = atomicAdd(&cnt[L], 1u);
      if (pos < (unsigned)CAP) {
        ck[(size_t)L * CAP + pos] = f2key64(v);
        cidx[(size_t)L * CAP + pos] = (unsigned)i;
      }
    }
  }
}

// one-block-per-level bitonic sort: (fp64 score desc, idx asc); emits top-512 (idx, valid)
__global__ void sort_k(const unsigned long long* __restrict__ ckA, const unsigned* __restrict__ cidxA,
                       const unsigned* __restrict__ cnt, uint2* __restrict__ topkA) {
  __shared__ unsigned long long k_[CAP];
  __shared__ unsigned x_[CAP];
  int L = blockIdx.x;
  const unsigned long long* ck = ckA + (size_t)L * CAP;
  const unsigned* cidx = cidxA + (size_t)L * CAP;
  uint2* topk = topkA + (size_t)L * KCAND;
  int t = threadIdx.x;
  unsigned m = cnt[L]; if (m > (unsigned)CAP) m = CAP;
  int sz = 512; while (sz < (int)m) sz <<= 1;   // m >= 512 guaranteed
  for (int i = t; i < sz; i += 1024) {
    if (i < (int)m) { k_[i] = ck[i]; x_[i] = cidx[i]; }
    else            { k_[i] = 0ULL;  x_[i] = 0xFFFFFFFFu; }
  }
  __syncthreads();
  for (int kk = 2; kk <= sz; kk <<= 1) {
    for (int j = kk >> 1; j > 0; j >>= 1) {
      for (int i = t; i < sz; i += 1024) {
        int l = i ^ j;
        if (l > i) {
          unsigned long long ka = k_[i], kb = k_[l];
          unsigned ia = x_[i], ib = x_[l];
          bool b_first = (kb > ka) || (kb == ka && ib < ia);  // b ranks before a?
          bool up = (i & kk) == 0;                            // descending region
          if (up == b_first) { k_[i] = kb; x_[i] = ib; k_[l] = ka; x_[l] = ia; }
        }
      }
      __syncthreads();
    }
  }
  if (t < KCAND) {
    unsigned long long key = k_[t];
    unsigned long long bb = (key >> 63) ? (key & 0x7FFFFFFFFFFFFFFFULL) : ~key;
    double sc = __longlong_as_double((long long)bb);
    topk[t] = make_uint2(x_[t], sc > 0.5 ? 1u : 0u);
  }
}

// ---------------- per-candidate cube stats + MLP (fp64 math, fp32 data); batched levels ----------------
__global__ __launch_bounds__(64) void mlp_k(const uint2* __restrict__ topkA,
                                            const float* __restrict__ pa, const float* __restrict__ pb,
                                            const float* __restrict__ pc_,
                                            const float* __restrict__ w1, const float* __restrict__ b1,
                                            const float* __restrict__ w2, const float* __restrict__ b2,
                                            float* __restrict__ out) {
  __shared__ double lhi[64];
  int L = blockIdx.y;
  int s = blockIdx.x;
  const float* p = L == 0 ? pa : (L == 1 ? pb : pc_);
  int D = 48 >> L, H = 96 >> L, W = 96 >> L;
  uint2 e = topkA[(size_t)L * KCAND + s];
  unsigned idx = e.x;
  double valid = e.y ? 1.0 : 0.0;
  int HW = H * W;
  int z = (int)(idx / (unsigned)HW);
  int r = (int)(idx % (unsigned)HW);
  int y = r / W; int x = r % W;
  int zs = min(max(z - 2, 0), D - 4);
  int ys = min(max(y - 2, 0), H - 4);
  int xs = min(max(x - 2, 0), W - 4);
  int t = threadIdx.x;
  int c = t & 31, h = t >> 5;
  const float* pc = p + (size_t)c * D * HW;
  double sum = 0.0, ss = 0.0;
  for (int i = 0; i < 32; i++) {
    int vv = h * 32 + i;
    int dz = vv >> 4, dy = (vv >> 2) & 3, dx = vv & 3;
    double val = (double)pc[(zs + dz) * HW + (ys + dy) * W + (xs + dx)];
    sum += val; ss = fma(val, val, ss);
  }
  sum += __shfl_xor(sum, 32);
  ss  += __shfl_xor(ss, 32);
  if (h == 0) {
    double mean = sum * (1.0 / 64.0);
    double var = ss * (1.0 / 64.0) - mean * mean;
    lhi[c] = mean;
    lhi[32 + c] = sqrt(var + 1e-6);
  }
  __syncthreads();
  double h0 = (double)b1[t], h1 = (double)b1[t + 64];
  for (int i = 0; i < 64; i++) {
    double li = lhi[i];
    h0 = fma(li, (double)w1[i * 128 + t], h0);
    h1 = fma(li, (double)w1[i * 128 + t + 64], h1);
  }
  h0 = fmax(h0, 0.0); h1 = fmax(h1, 0.0);
  double o0 = h0 * (double)w2[t * 2 + 0] + h1 * (double)w2[(t + 64) * 2 + 0];
  double o1 = h0 * (double)w2[t * 2 + 1] + h1 * (double)w2[(t + 64) * 2 + 1];
  for (int o = 1; o < 64; o <<= 1) { o0 += __shfl_xor(o0, o); o1 += __shfl_xor(o1, o); }
  if (t == 0) {
    out[((size_t)L * KCAND + s) * 2 + 0] = (float)((o0 + (double)b2[0]) * valid);
    out[((size_t)L * KCAND + s) * 2 + 1] = (float)((o1 + (double)b2[1]) * valid);
  }
}

// ---------------- launch ----------------
extern "C" void kernel_launch(void* const* d_in, const int* in_sizes, int n_in,
                              void* d_out, int out_size, void* d_ws, size_t ws_size,
                              hipStream_t stream) {
  const float* x   = (const float*)d_in[0];
  const float* c1w = (const float*)d_in[1];  const float* c1b = (const float*)d_in[2];
  const float* c2w = (const float*)d_in[3];  const float* c2b = (const float*)d_in[4];
  const float* c3w = (const float*)d_in[5];  const float* c3b = (const float*)d_in[6];
  const float* l1w = (const float*)d_in[7];  const float* l1b = (const float*)d_in[8];
  const float* l2w = (const float*)d_in[9];  const float* l2b = (const float*)d_in[10];
  const float* l3w = (const float*)d_in[11]; const float* l3b = (const float*)d_in[12];
  const float* w1  = (const float*)d_in[13]; const float* b1  = (const float*)d_in[14];
  const float* w2  = (const float*)d_in[15]; const float* b2  = (const float*)d_in[16];
  float* out = (float*)d_out;

  char* ws = (char*)d_ws;
  size_t off = 0;
  auto take = [&](size_t bytes) { size_t o = off; off = (off + bytes + 255) & ~(size_t)255; return o; };
  double* f1d = (double*)(ws + take((size_t)16 * PN1 * 8));
  double* f2d = (double*)(ws + take((size_t)32 * PN2 * 8));
  double* f3d = (double*)(ws + take((size_t)64 * N3 * 8));
  float*  p1f = (float*) (ws + take((size_t)32 * N1 * 4));
  double* p2d = (double*)(ws + take((size_t)32 * N2 * 8));
  float*  p2f = (float*) (ws + take((size_t)32 * N2 * 4));
  double* p3d = (double*)(ws + take((size_t)32 * N3 * 8));
  float*  p3f = (float*) (ws + take((size_t)32 * N3 * 4));
  double* s1 = (double*)(ws + take((size_t)N1 * 8));
  double* s2 = (double*)(ws + take((size_t)N2 * 8));
  double* s3 = (double*)(ws + take((size_t)N3 * 8));
  // selection scratch: hist1[3*256] hist2[3*256] cnt[3] (zeroed) + meta[12] (always written)
  size_t zOff = take((3 * 256 + 3 * 256 + 3) * 4);
  unsigned* hist1 = (unsigned*)(ws + zOff);
  unsigned* hist2 = hist1 + 3 * 256;
  unsigned* cnt   = hist2 + 3 * 256;
  unsigned* meta  = (unsigned*)(ws + take(12 * 4));
  unsigned long long* candKey = (unsigned long long*)(ws + take((size_t)3 * CAP * 8));
  unsigned* candIdx = (unsigned*)(ws + take((size_t)3 * CAP * 4));
  uint2* topk = (uint2*)(ws + take((size_t)3 * KCAND * 8));

  hipMemsetAsync(ws + zOff, 0, (3 * 256 + 3 * 256 + 3) * 4, stream);

  // encoder (fp64, padded intermediates, branch-free taps)
  conv1_k<<<(PV1 + 255) / 256, 256, 0, stream>>>(x, c1w, c1b, f1d);
  conv2_k<<<dim3((PV2 + 255) / 256, 4), 256, 0, stream>>>(f1d, c2w, c2b, f2d);
  conv3_k<<<dim3(N3 / 256, 16), 256, 0, stream>>>(f2d, c3w, c3b, f3d);
  // FPN top-down (fp64 + fp32 copies)
  p3_k<<<N3 / 256, 256, 0, stream>>>(f3d, l3w, l3b, p3d, p3f, s3);
  p2_k<<<N2 / 256, 256, 0, stream>>>(f2d, l2w, l2b, p3d, p2d, p2f, s2);
  p1_k<<<N1 / 256, 256, 0, stream>>>(f1d, l1w, l1b, p2d, p1f, s1);

  // selection (batched across 3 levels)
  hist1_k<<<dim3(64, 3), 256, 0, stream>>>(s1, s2, s3, hist1);
  pick1_k<<<1, 64, 0, stream>>>(hist1, meta);
  hist2_k<<<dim3(64, 3), 256, 0, stream>>>(s1, s2, s3, meta, hist2);
  pick2_k<<<1, 64, 0, stream>>>(hist2, meta);
  compact_k<<<dim3(112, 3), 256, 0, stream>>>(s1, s2, s3, meta, candKey, candIdx, cnt);
  sort_k<<<3, 1024, 0, stream>>>(candKey, candIdx, cnt, topk);
  mlp_k<<<dim3(KCAND, 3), 64, 0, stream>>>(topk, p1f, p2f, p3f, w1, b1, w2, b2, out);
}

// Round 6
// 445.454 us; speedup vs baseline: 5.4048x; 1.0813x over previous
//
#include <hip/hip_runtime.h>
#include <hip/hip_bf16.h>
#include <cstdint>
#include <cstddef>

// ---------------- sizes ----------------
#define N1 442368   // 48*96*96 spatial (p1, s1)
#define N2 55296    // 24*48*48 spatial (p2, s2)
#define N3 6912     // 12*24*24 spatial (p3, s3)

// padded fp64 feature layouts (pad at high edge so conv taps are branch-free)
#define PZ1 9409    // 97*97
#define PN1 461041  // 49*97*97
#define PV1 461041
#define PZ2 2401    // 49*49
#define PN2 60025   // 25*49*49
#define PV2 60025

#define KCAND 512
#define CAP   4096

// ---------------- helpers ----------------
__device__ __forceinline__ unsigned long long f2key64(double f) {
  unsigned long long b = (unsigned long long)__double_as_longlong(f);
  return (b & 0x8000000000000000ULL) ? ~b : (b | 0x8000000000000000ULL);
}
__device__ __forceinline__ unsigned f2key32(float f) {
  unsigned b = __float_as_uint(f);
  return (b & 0x80000000u) ? ~b : (b | 0x80000000u);
}

// ---------------- conv1: 1->16ch, in 96x192x192, out padded [16][49][97][97] ----------------
__global__ __launch_bounds__(256) void conv1_k(const float* __restrict__ x, const float* __restrict__ w,
                                               const float* __restrict__ b, double* __restrict__ f1) {
  __shared__ __align__(16) double wsD[27 * 16];  // [t][c], fp64 (no cvt in inner loop)
  for (int i = threadIdx.x; i < 27 * 16; i += 256) {
    int t = i >> 4, c = i & 15;
    wsD[i] = (double)w[c * 27 + t];
  }
  __syncthreads();
  int v = blockIdx.x * 256 + threadIdx.x;
  if (v >= PV1) return;
  int z = v / PZ1; int r = v % PZ1; int y = r / 97; int xo = r % 97;
  if (z >= 48 || y >= 96 || xo >= 96) {
#pragma unroll
    for (int c = 0; c < 16; c++) f1[(size_t)c * PN1 + v] = 0.0;
    return;
  }
  float val[27];
#pragma unroll
  for (int dz = 0; dz < 3; dz++)
#pragma unroll
    for (int dy = 0; dy < 3; dy++)
#pragma unroll
      for (int dx = 0; dx < 3; dx++) {
        int zi = 2 * z + dz, yi = 2 * y + dy, xi = 2 * xo + dx;
        bool ok = (zi < 96) & (yi < 192) & (xi < 192);
        int zc = min(zi, 95), yc = min(yi, 191), xc = min(xi, 191);
        float t = x[(zc * 192 + yc) * 192 + xc];
        val[(dz * 3 + dy) * 3 + dx] = ok ? t : 0.0f;
      }
  double acc[16];
#pragma unroll
  for (int c = 0; c < 16; c++) acc[c] = (double)b[c];
#pragma unroll
  for (int t = 0; t < 27; t++) {
    double vv = (double)val[t];
#pragma unroll
    for (int c = 0; c < 16; c++) acc[c] = fma(vv, wsD[t * 16 + c], acc[c]);
  }
#pragma unroll
  for (int c = 0; c < 16; c++) f1[(size_t)c * PN1 + v] = fmax(acc[c], 0.0);
}

// ---------------- conv2: 16->32ch, out padded [32][25][49][49]; gridDim.y=2 groups of 16 ----------------
__global__ __launch_bounds__(256) void conv2_k(const double* __restrict__ f1, const float* __restrict__ w,
                                               const float* __restrict__ b, double* __restrict__ f2) {
  __shared__ __align__(16) double wsD[16 * 27 * 16];  // [ci][t][c] 55.3 KB
  int g = blockIdx.y;  // 16 output channels per group
  for (int i = threadIdx.x; i < 16 * 27 * 16; i += 256) {
    int ci = i / 432, rem = i % 432, t = rem >> 4, c = rem & 15;
    wsD[i] = (double)w[((size_t)(g * 16 + c) * 16 + ci) * 27 + t];
  }
  __syncthreads();
  int v = blockIdx.x * 256 + threadIdx.x;
  if (v >= PV2) return;
  int z = v / PZ2; int r = v % PZ2; int y = r / 49; int xo = r % 49;
  if (z >= 24 || y >= 48 || xo >= 48) {
#pragma unroll
    for (int c = 0; c < 16; c++) f2[(size_t)(g * 16 + c) * PN2 + v] = 0.0;
    return;
  }
  double acc[16];
#pragma unroll
  for (int c = 0; c < 16; c++) acc[c] = (double)b[g * 16 + c];
  const double* base = f1 + (size_t)(2 * z) * PZ1 + (2 * y) * 97 + 2 * xo;
  for (int ci = 0; ci < 16; ci++) {
    const double* fp = base + (size_t)ci * PN1;
    double vals[27];
#pragma unroll
    for (int dz = 0; dz < 3; dz++)
#pragma unroll
      for (int dy = 0; dy < 3; dy++)
#pragma unroll
        for (int dx = 0; dx < 3; dx++)
          vals[(dz * 3 + dy) * 3 + dx] = fp[dz * PZ1 + dy * 97 + dx];
#pragma unroll
    for (int t = 0; t < 27; t++) {
      double vv = vals[t];
      const double* wp = &wsD[(ci * 27 + t) * 16];
#pragma unroll
      for (int c = 0; c < 16; c++) acc[c] = fma(vv, wp[c], acc[c]);
    }
  }
#pragma unroll
  for (int c = 0; c < 16; c++) f2[(size_t)(g * 16 + c) * PN2 + v] = fmax(acc[c], 0.0);
}

// ---------------- conv3: 32->64ch, out [64][6912]; gridDim.y=16 groups of 4 ----------------
__global__ __launch_bounds__(256) void conv3_k(const double* __restrict__ f2, const float* __restrict__ w,
                                               const float* __restrict__ b, double* __restrict__ f3) {
  __shared__ __align__(16) double wsD[32 * 27 * 4];  // [ci][t][c] 27.6 KB
  int g = blockIdx.y;
  for (int i = threadIdx.x; i < 32 * 27 * 4; i += 256) {
    int ci = i / 108, rem = i % 108, t = rem >> 2, c = rem & 3;
    wsD[i] = (double)w[((size_t)(g * 4 + c) * 32 + ci) * 27 + t];
  }
  __syncthreads();
  int v = blockIdx.x * 256 + threadIdx.x;
  if (v >= N3) return;
  int z = v / 576; int r = v % 576; int y = r / 24; int xo = r % 24;
  double acc[4];
#pragma unroll
  for (int c = 0; c < 4; c++) acc[c] = (double)b[g * 4 + c];
  const double* base = f2 + (size_t)(2 * z) * PZ2 + (2 * y) * 49 + 2 * xo;
  for (int ci = 0; ci < 32; ci++) {
    const double* fp = base + (size_t)ci * PN2;
    double vals[27];
#pragma unroll
    for (int dz = 0; dz < 3; dz++)
#pragma unroll
      for (int dy = 0; dy < 3; dy++)
#pragma unroll
        for (int dx = 0; dx < 3; dx++)
          vals[(dz * 3 + dy) * 3 + dx] = fp[dz * PZ2 + dy * 49 + dx];
#pragma unroll
    for (int t = 0; t < 27; t++) {
      double vv = vals[t];
      const double* wp = &wsD[(ci * 27 + t) * 4];
#pragma unroll
      for (int c = 0; c < 4; c++) acc[c] = fma(vv, wp[c], acc[c]);
    }
  }
#pragma unroll
  for (int c = 0; c < 4; c++) f3[(size_t)(g * 4 + c) * N3 + v] = fmax(acc[c], 0.0);
}

// ---------------- p3 = l3(f3); score3 ----------------
__global__ __launch_bounds__(256) void p3_k(const double* __restrict__ f3, const float* __restrict__ w,
                                            const float* __restrict__ b, double* __restrict__ p3d,
                                            float* __restrict__ p3f, double* __restrict__ s3) {
  __shared__ __align__(16) double wsD[64 * 32];  // [ci][c] 16 KB
  for (int i = threadIdx.x; i < 64 * 32; i += 256) {
    int ci = i >> 5, c = i & 31;
    wsD[i] = (double)w[c * 64 + ci];
  }
  __syncthreads();
  int v = blockIdx.x * 256 + threadIdx.x;
  if (v >= N3) return;
  double acc[32];
#pragma unroll
  for (int c = 0; c < 32; c++) acc[c] = (double)b[c];
  for (int ci = 0; ci < 64; ci++) {
    double vv = f3[(size_t)ci * N3 + v];
    const double* wp = &wsD[ci * 32];
#pragma unroll
    for (int c = 0; c < 32; c++) acc[c] = fma(vv, wp[c], acc[c]);
  }
  double m = -1e300;
#pragma unroll
  for (int c = 0; c < 32; c++) {
    p3d[(size_t)c * N3 + v] = acc[c];
    p3f[(size_t)c * N3 + v] = (float)acc[c];
    m = fmax(m, acc[c]);
  }
  s3[v] = m;
}

// ---------------- p2 = l2(f2) + up2(p3); score2 ----------------
__global__ __launch_bounds__(256) void p2_k(const double* __restrict__ f2, const float* __restrict__ w,
                                            const float* __restrict__ b, const double* __restrict__ p3d,
                                            double* __restrict__ p2d, float* __restrict__ p2f, double* __restrict__ s2) {
  __shared__ __align__(16) double wsD[32 * 32];  // [ci][c] 8 KB
  for (int i = threadIdx.x; i < 32 * 32; i += 256) {
    int ci = i >> 5, c = i & 31;
    wsD[i] = (double)w[c * 32 + ci];
  }
  __syncthreads();
  int v = blockIdx.x * 256 + threadIdx.x;
  if (v >= N2) return;
  int z = v / (48 * 48); int r = v % (48 * 48); int y = r / 48; int xo = r % 48;
  int pidx = z * PZ2 + y * 49 + xo;  // padded f2 voxel
  int up = ((z >> 1) * 24 + (y >> 1)) * 24 + (xo >> 1);
  double acc[32];
#pragma unroll
  for (int c = 0; c < 32; c++) acc[c] = (double)b[c];
  for (int ci = 0; ci < 32; ci++) {
    double vv = f2[(size_t)ci * PN2 + pidx];
    const double* wp = &wsD[ci * 32];
#pragma unroll
    for (int c = 0; c < 32; c++) acc[c] = fma(vv, wp[c], acc[c]);
  }
  double m = -1e300;
#pragma unroll
  for (int c = 0; c < 32; c++) {
    double o = acc[c] + p3d[(size_t)c * N3 + up];
    p2d[(size_t)c * N2 + v] = o;
    p2f[(size_t)c * N2 + v] = (float)o;
    m = fmax(m, o);
  }
  s2[v] = m;
}

// ---------------- p1 score only (no p1 materialization) ----------------
__global__ __launch_bounds__(256) void p1_k(const double* __restrict__ f1, const float* __restrict__ w,
                                            const float* __restrict__ b, const double* __restrict__ p2d,
                                            double* __restrict__ s1) {
  __shared__ __align__(16) double wsD[16 * 32];  // [ci][c] 4 KB
  for (int i = threadIdx.x; i < 16 * 32; i += 256) {
    int ci = i >> 5, c = i & 31;
    wsD[i] = (double)w[c * 16 + ci];
  }
  __syncthreads();
  int v = blockIdx.x * 256 + threadIdx.x;
  if (v >= N1) return;
  int z = v / (96 * 96); int r = v % (96 * 96); int y = r / 96; int xo = r % 96;
  int pidx = z * PZ1 + y * 97 + xo;  // padded f1 voxel
  int up = ((z >> 1) * 48 + (y >> 1)) * 48 + (xo >> 1);
  double acc[32];
#pragma unroll
  for (int c = 0; c < 32; c++) acc[c] = (double)b[c];
  for (int ci = 0; ci < 16; ci++) {
    double vv = f1[(size_t)ci * PN1 + pidx];
    const double* wp = &wsD[ci * 32];
#pragma unroll
    for (int c = 0; c < 32; c++) acc[c] = fma(vv, wp[c], acc[c]);
  }
  double m = -1e300;
#pragma unroll
  for (int c = 0; c < 32; c++) m = fmax(m, acc[c] + p2d[(size_t)c * N2 + up]);
  s1[v] = m;
}

// ---------------- selection: two-pass 256-bin radix over fp32 key, batched over levels ----------------
__global__ void hist1_k(const double* __restrict__ s1, const double* __restrict__ s2,
                        const double* __restrict__ s3, unsigned* __restrict__ hist) {
  int L = blockIdx.y;
  const double* s = L == 0 ? s1 : (L == 1 ? s2 : s3);
  int n = L == 0 ? N1 : (L == 1 ? N2 : N3);
  unsigned* hg = hist + L * 256;
  __shared__ unsigned h[256];
  h[threadIdx.x] = 0;
  __syncthreads();
  for (int i = blockIdx.x * 256 + threadIdx.x; i < n; i += gridDim.x * 256)
    atomicAdd(&h[f2key32((float)s[i]) >> 24], 1u);
  __syncthreads();
  unsigned v = h[threadIdx.x];
  if (v) atomicAdd(&hg[threadIdx.x], v);
}

__global__ void pick1_k(const unsigned* __restrict__ hist, unsigned* __restrict__ meta) {
  int L = threadIdx.x;
  if (L >= 3) return;
  const unsigned* hg = hist + L * 256;
  unsigned run = 0; int b = 0;
  for (int i = 255; i >= 0; i--) {
    unsigned c = hg[i];
    if (run + c >= (unsigned)KCAND) { b = i; break; }
    run += c;
  }
  meta[L * 4 + 0] = (unsigned)b;
  meta[L * 4 + 1] = run;
}

__global__ void hist2_k(const double* __restrict__ s1, const double* __restrict__ s2,
                        const double* __restrict__ s3, const unsigned* __restrict__ meta,
                        unsigned* __restrict__ hist2) {
  int L = blockIdx.y;
  const double* s = L == 0 ? s1 : (L == 1 ? s2 : s3);
  int n = L == 0 ? N1 : (L == 1 ? N2 : N3);
  unsigned b1 = meta[L * 4 + 0];
  unsigned* hg = hist2 + L * 256;
  __shared__ unsigned h[256];
  h[threadIdx.x] = 0;
  __syncthreads();
  for (int i = blockIdx.x * 256 + threadIdx.x; i < n; i += gridDim.x * 256) {
    unsigned k = f2key32((float)s[i]);
    if ((k >> 24) == b1) atomicAdd(&h[(k >> 16) & 255u], 1u);
  }
  __syncthreads();
  unsigned v = h[threadIdx.x];
  if (v) atomicAdd(&hg[threadIdx.x], v);
}

__global__ void pick2_k(const unsigned* __restrict__ hist2, unsigned* __restrict__ meta) {
  int L = threadIdx.x;
  if (L >= 3) return;
  const unsigned* hg = hist2 + L * 256;
  unsigned b1 = meta[L * 4 + 0];
  unsigned run = meta[L * 4 + 1];
  unsigned b2 = 0;
  for (int i = 255; i >= 0; i--) {
    run += hg[i];
    if (run >= (unsigned)KCAND) { b2 = (unsigned)i; break; }
  }
  meta[L * 4 + 2] = (b1 << 24) | (b2 << 16);
}

__global__ void compact_k(const double* __restrict__ s1, const double* __restrict__ s2,
                          const double* __restrict__ s3, const unsigned* __restrict__ meta,
                          unsigned long long* __restrict__ ck, unsigned* __restrict__ cidx,
                          unsigned* __restrict__ cnt) {
  int L = blockIdx.y;
  const double* s = L == 0 ? s1 : (L == 1 ? s2 : s3);
  int n = L == 0 ? N1 : (L == 1 ? N2 : N3);
  unsigned T = meta[L * 4 + 2];
  for (int i = blockIdx.x * 256 + threadIdx.x; i < n; i += gridDim.x * 256) {
    double v = s[i];
    if (f2key32((float)v) >= T) {
      unsigned pos = atomicAdd(&cnt[L], 1u);
      if (pos < (unsigned)CAP) {
        ck[(size_t)L * CAP + pos] = f2key64(v);
        cidx[(size_t)L * CAP + pos] = (unsigned)i;
      }
    }
  }
}

// one-block-per-level bitonic sort: (fp64 score desc, idx asc); emits top-512 (idx, valid)
__global__ void sort_k(const unsigned long long* __restrict__ ckA, const unsigned* __restrict__ cidxA,
                       const unsigned* __restrict__ cnt, uint2* __restrict__ topkA) {
  __shared__ unsigned long long k_[CAP];
  __shared__ unsigned x_[CAP];
  int L = blockIdx.x;
  const unsigned long long* ck = ckA + (size_t)L * CAP;
  const unsigned* cidx = cidxA + (size_t)L * CAP;
  uint2* topk = topkA + (size_t)L * KCAND;
  int t = threadIdx.x;
  unsigned m = cnt[L]; if (m > (unsigned)CAP) m = CAP;
  int sz = 512; while (sz < (int)m) sz <<= 1;   // m >= 512 guaranteed
  for (int i = t; i < sz; i += 1024) {
    if (i < (int)m) { k_[i] = ck[i]; x_[i] = cidx[i]; }
    else            { k_[i] = 0ULL;  x_[i] = 0xFFFFFFFFu; }
  }
  __syncthreads();
  for (int kk = 2; kk <= sz; kk <<= 1) {
    for (int j = kk >> 1; j > 0; j >>= 1) {
      for (int i = t; i < sz; i += 1024) {
        int l = i ^ j;
        if (l > i) {
          unsigned long long ka = k_[i], kb = k_[l];
          unsigned ia = x_[i], ib = x_[l];
          bool b_first = (kb > ka) || (kb == ka && ib < ia);  // b ranks before a?
          bool up = (i & kk) == 0;                            // descending region
          if (up == b_first) { k_[i] = kb; x_[i] = ib; k_[l] = ka; x_[l] = ia; }
        }
      }
      __syncthreads();
    }
  }
  if (t < KCAND) {
    unsigned long long key = k_[t];
    unsigned long long bb = (key >> 63) ? (key & 0x7FFFFFFFFFFFFFFFULL) : ~key;
    double sc = __longlong_as_double((long long)bb);
    topk[t] = make_uint2(x_[t], sc > 0.5 ? 1u : 0u);
  }
}

// ---------------- per-candidate cube stats + MLP; L=0 computes cubes on-the-fly ----------------
__global__ __launch_bounds__(64) void mlp_k(const uint2* __restrict__ topkA,
                                            const double* __restrict__ f1d, const double* __restrict__ p2d,
                                            const float* __restrict__ p2f, const float* __restrict__ p3f,
                                            const float* __restrict__ l1w, const float* __restrict__ l1b,
                                            const float* __restrict__ w1, const float* __restrict__ b1,
                                            const float* __restrict__ w2, const float* __restrict__ b2,
                                            float* __restrict__ out) {
  __shared__ double lhi[64];
  __shared__ double f1c[16 * 64];   // [ci][voxel]
  __shared__ double wsD[16 * 32];   // [ci][c]
  int L = blockIdx.y;
  int s = blockIdx.x;
  int D = 48 >> L, H = 96 >> L, W = 96 >> L;
  uint2 e = topkA[(size_t)L * KCAND + s];
  unsigned idx = e.x;
  double valid = e.y ? 1.0 : 0.0;
  int HW = H * W;
  int z = (int)(idx / (unsigned)HW);
  int r = (int)(idx % (unsigned)HW);
  int y = r / W; int x = r % W;
  int zs = min(max(z - 2, 0), D - 4);
  int ys = min(max(y - 2, 0), H - 4);
  int xs = min(max(x - 2, 0), W - 4);
  int t = threadIdx.x;
  int c = t & 31, h = t >> 5;
  double sum = 0.0, ss = 0.0;
  if (L == 0) {
    for (int i = t; i < 512; i += 64) wsD[i] = (double)l1w[(i & 31) * 16 + (i >> 5)];
    for (int i = t; i < 1024; i += 64) {
      int ci = i >> 6, v = i & 63;
      int dz = v >> 4, dy = (v >> 2) & 3, dx = v & 3;
      f1c[i] = f1d[(size_t)ci * PN1 + (zs + dz) * PZ1 + (ys + dy) * 97 + (xs + dx)];
    }
    __syncthreads();
    double bc = (double)l1b[c];
    for (int i = 0; i < 32; i++) {
      int vv = h * 32 + i;
      int dz = vv >> 4, dy = (vv >> 2) & 3, dx = vv & 3;
      int up = (((zs + dz) >> 1) * 48 + ((ys + dy) >> 1)) * 48 + ((xs + dx) >> 1);
      double val = bc + p2d[(size_t)c * N2 + up];
#pragma unroll
      for (int ci = 0; ci < 16; ci++)
        val = fma(f1c[ci * 64 + vv], wsD[ci * 32 + c], val);
      sum += val; ss = fma(val, val, ss);
    }
  } else {
    const float* p = (L == 1) ? p2f : p3f;
    const float* pc = p + (size_t)c * D * HW;
    for (int i = 0; i < 32; i++) {
      int vv = h * 32 + i;
      int dz = vv >> 4, dy = (vv >> 2) & 3, dx = vv & 3;
      double val = (double)pc[(zs + dz) * HW + (ys + dy) * W + (xs + dx)];
      sum += val; ss = fma(val, val, ss);
    }
  }
  sum += __shfl_xor(sum, 32);
  ss  += __shfl_xor(ss, 32);
  if (h == 0) {
    double mean = sum * (1.0 / 64.0);
    double var = ss * (1.0 / 64.0) - mean * mean;
    lhi[c] = mean;
    lhi[32 + c] = sqrt(var + 1e-6);
  }
  __syncthreads();
  double h0 = (double)b1[t], h1 = (double)b1[t + 64];
  for (int i = 0; i < 64; i++) {
    double li = lhi[i];
    h0 = fma(li, (double)w1[i * 128 + t], h0);
    h1 = fma(li, (double)w1[i * 128 + t + 64], h1);
  }
  h0 = fmax(h0, 0.0); h1 = fmax(h1, 0.0);
  double o0 = h0 * (double)w2[t * 2 + 0] + h1 * (double)w2[(t + 64) * 2 + 0];
  double o1 = h0 * (double)w2[t * 2 + 1] + h1 * (double)w2[(t + 64) * 2 + 1];
  for (int o = 1; o < 64; o <<= 1) { o0 += __shfl_xor(o0, o); o1 += __shfl_xor(o1, o); }
  if (t == 0) {
    out[((size_t)L * KCAND + s) * 2 + 0] = (float)((o0 + (double)b2[0]) * valid);
    out[((size_t)L * KCAND + s) * 2 + 1] = (float)((o1 + (double)b2[1]) * valid);
  }
}

// ---------------- launch ----------------
extern "C" void kernel_launch(void* const* d_in, const int* in_sizes, int n_in,
                              void* d_out, int out_size, void* d_ws, size_t ws_size,
                              hipStream_t stream) {
  const float* x   = (const float*)d_in[0];
  const float* c1w = (const float*)d_in[1];  const float* c1b = (const float*)d_in[2];
  const float* c2w = (const float*)d_in[3];  const float* c2b = (const float*)d_in[4];
  const float* c3w = (const float*)d_in[5];  const float* c3b = (const float*)d_in[6];
  const float* l1w = (const float*)d_in[7];  const float* l1b = (const float*)d_in[8];
  const float* l2w = (const float*)d_in[9];  const float* l2b = (const float*)d_in[10];
  const float* l3w = (const float*)d_in[11]; const float* l3b = (const float*)d_in[12];
  const float* w1  = (const float*)d_in[13]; const float* b1  = (const float*)d_in[14];
  const float* w2  = (const float*)d_in[15]; const float* b2  = (const float*)d_in[16];
  float* out = (float*)d_out;

  char* ws = (char*)d_ws;
  size_t off = 0;
  auto take = [&](size_t bytes) { size_t o = off; off = (off + bytes + 255) & ~(size_t)255; return o; };
  double* f1d = (double*)(ws + take((size_t)16 * PN1 * 8));
  double* f2d = (double*)(ws + take((size_t)32 * PN2 * 8));
  double* f3d = (double*)(ws + take((size_t)64 * N3 * 8));
  double* p2d = (double*)(ws + take((size_t)32 * N2 * 8));
  float*  p2f = (float*) (ws + take((size_t)32 * N2 * 4));
  double* p3d = (double*)(ws + take((size_t)32 * N3 * 8));
  float*  p3f = (float*) (ws + take((size_t)32 * N3 * 4));
  double* s1 = (double*)(ws + take((size_t)N1 * 8));
  double* s2 = (double*)(ws + take((size_t)N2 * 8));
  double* s3 = (double*)(ws + take((size_t)N3 * 8));
  // selection scratch: hist1[3*256] hist2[3*256] cnt[3] (zeroed) + meta[12] (always written)
  size_t zOff = take((3 * 256 + 3 * 256 + 3) * 4);
  unsigned* hist1 = (unsigned*)(ws + zOff);
  unsigned* hist2 = hist1 + 3 * 256;
  unsigned* cnt   = hist2 + 3 * 256;
  unsigned* meta  = (unsigned*)(ws + take(12 * 4));
  unsigned long long* candKey = (unsigned long long*)(ws + take((size_t)3 * CAP * 8));
  unsigned* candIdx = (unsigned*)(ws + take((size_t)3 * CAP * 4));
  uint2* topk = (uint2*)(ws + take((size_t)3 * KCAND * 8));

  hipMemsetAsync(ws + zOff, 0, (3 * 256 + 3 * 256 + 3) * 4, stream);

  // encoder (fp64, padded intermediates, branch-free taps, fp64 LDS weights)
  conv1_k<<<(PV1 + 255) / 256, 256, 0, stream>>>(x, c1w, c1b, f1d);
  conv2_k<<<dim3((PV2 + 255) / 256, 2), 256, 0, stream>>>(f1d, c2w, c2b, f2d);
  conv3_k<<<dim3(N3 / 256, 16), 256, 0, stream>>>(f2d, c3w, c3b, f3d);
  // FPN top-down
  p3_k<<<N3 / 256, 256, 0, stream>>>(f3d, l3w, l3b, p3d, p3f, s3);
  p2_k<<<N2 / 256, 256, 0, stream>>>(f2d, l2w, l2b, p3d, p2d, p2f, s2);
  p1_k<<<N1 / 256, 256, 0, stream>>>(f1d, l1w, l1b, p2d, s1);

  // selection (batched across 3 levels)
  hist1_k<<<dim3(64, 3), 256, 0, stream>>>(s1, s2, s3, hist1);
  pick1_k<<<1, 64, 0, stream>>>(hist1, meta);
  hist2_k<<<dim3(64, 3), 256, 0, stream>>>(s1, s2, s3, meta, hist2);
  pick2_k<<<1, 64, 0, stream>>>(hist2, meta);
  compact_k<<<dim3(112, 3), 256, 0, stream>>>(s1, s2, s3, meta, candKey, candIdx, cnt);
  sort_k<<<3, 1024, 0, stream>>>(candKey, candIdx, cnt, topk);
  mlp_k<<<dim3(KCAND, 3), 64, 0, stream>>>(topk, f1d, p2d, p2f, p3f, l1w, l1b,
                                           w1, b1, w2, b2, out);
}